// Round 1
// baseline (1795.477 us; speedup 1.0000x reference)
//
#include <hip/hip_runtime.h>
#include <cmath>

// Problem constants
#define Bv   2
#define Tv   8
#define Hv   64
#define Wv   64
#define Cv   128
#define NHv  4
#define HDv  32
#define KTv  3
#define KHv  7
#define KWv  7
#define MPOS (Bv*Tv*Hv*Wv)          // 65536 query positions
#define SCALEv 0.17677669529663687f  // 32^-0.5

// ---------------------------------------------------------------------------
// GEMM A[M,128] @ W[128,256] + bias -> split into q (cols 0..127) / v (128..255)
// block: 256 threads = 64 col-threads x 4 row-groups; 32 rows per block.
// Each thread: 4 cols x 8 rows => each ds_read_b128 of x feeds 16 FMAs.
// ---------------------------------------------------------------------------
__global__ __launch_bounds__(256) void gemm_qv(
    const float* __restrict__ x, const float* __restrict__ w,
    const float* __restrict__ bias,
    float* __restrict__ qout, float* __restrict__ vout) {
  __shared__ float xs[32][128];
  const int tid  = threadIdx.x;
  const int row0 = blockIdx.x * 32;

  // stage x tile: 4096 floats = 1024 float4, 4 per thread
  {
    const float4* xg  = (const float4*)(x + (size_t)row0 * 128);
    float4*       xs4 = (float4*)&xs[0][0];
#pragma unroll
    for (int i = 0; i < 4; ++i) xs4[tid + 256 * i] = xg[tid + 256 * i];
  }
  __syncthreads();

  const int cl = tid & 63;   // column base (0..63), cols = cl + 64*i
  const int rg = tid >> 6;   // row group (0..3), rows rg*8 .. rg*8+7

  float acc[8][4];
#pragma unroll
  for (int r = 0; r < 8; ++r)
#pragma unroll
    for (int i = 0; i < 4; ++i) acc[r][i] = 0.f;

  for (int k0 = 0; k0 < 128; k0 += 4) {
    float wv[4][4];
#pragma unroll
    for (int j = 0; j < 4; ++j)
#pragma unroll
      for (int i = 0; i < 4; ++i)
        wv[j][i] = w[(k0 + j) * 256 + cl + 64 * i];
#pragma unroll
    for (int r = 0; r < 8; ++r) {
      float4 x4 = *(const float4*)&xs[rg * 8 + r][k0];
#pragma unroll
      for (int i = 0; i < 4; ++i)
        acc[r][i] += x4.x * wv[0][i] + x4.y * wv[1][i] +
                     x4.z * wv[2][i] + x4.w * wv[3][i];
    }
  }

#pragma unroll
  for (int r = 0; r < 8; ++r) {
    const size_t row = row0 + rg * 8 + r;
#pragma unroll
    for (int i = 0; i < 4; ++i) {
      const int col = cl + 64 * i;
      const float val = acc[r][i] + bias[col];
      if (col < 128) qout[row * 128 + col] = val;
      else           vout[row * 128 + (col - 128)] = val;
    }
  }
}

// ---------------------------------------------------------------------------
// GEMM A[M,128] @ W[128,128] + bias -> out[M,128]   (used for K proj and O proj)
// block: 256 threads = 64 col-threads x 4 row-groups; 32 rows; 2 cols x 8 rows.
// ---------------------------------------------------------------------------
__global__ __launch_bounds__(256) void gemm_n128(
    const float* __restrict__ a, const float* __restrict__ w,
    const float* __restrict__ bias, float* __restrict__ out) {
  __shared__ float xs[32][128];
  const int tid  = threadIdx.x;
  const int row0 = blockIdx.x * 32;
  {
    const float4* xg  = (const float4*)(a + (size_t)row0 * 128);
    float4*       xs4 = (float4*)&xs[0][0];
#pragma unroll
    for (int i = 0; i < 4; ++i) xs4[tid + 256 * i] = xg[tid + 256 * i];
  }
  __syncthreads();

  const int cl = tid & 63;
  const int rg = tid >> 6;

  float acc[8][2];
#pragma unroll
  for (int r = 0; r < 8; ++r) { acc[r][0] = 0.f; acc[r][1] = 0.f; }

  for (int k0 = 0; k0 < 128; k0 += 4) {
    float wv[4][2];
#pragma unroll
    for (int j = 0; j < 4; ++j)
#pragma unroll
      for (int i = 0; i < 2; ++i)
        wv[j][i] = w[(k0 + j) * 128 + cl + 64 * i];
#pragma unroll
    for (int r = 0; r < 8; ++r) {
      float4 x4 = *(const float4*)&xs[rg * 8 + r][k0];
#pragma unroll
      for (int i = 0; i < 2; ++i)
        acc[r][i] += x4.x * wv[0][i] + x4.y * wv[1][i] +
                     x4.z * wv[2][i] + x4.w * wv[3][i];
    }
  }

#pragma unroll
  for (int r = 0; r < 8; ++r) {
    const size_t row = row0 + rg * 8 + r;
#pragma unroll
    for (int i = 0; i < 2; ++i) {
      const int col = cl + 64 * i;
      out[row * 128 + col] = acc[r][i] + bias[col];
    }
  }
}

// ---------------------------------------------------------------------------
// NA3D attention: one 128-thread block per query position, all 4 heads.
// thread c: head = c>>5, dim = c&31. Online softmax over 147 neighbors.
// Writes output o (may alias q: each thread reads q[addr] before writing o[addr]).
// ---------------------------------------------------------------------------
__global__ __launch_bounds__(128) void na3d_attn(
    const float* q, const float* __restrict__ k, const float* __restrict__ v,
    const float* __restrict__ rpb, float* o) {
  const int pos = blockIdx.x;                 // ((b*T + t)*H + h)*W + w
  const int w_  = pos & 63;
  const int h_  = (pos >> 6) & 63;
  const int t_  = (pos >> 12) & 7;
  const int b   = pos >> 15;                  // T*H*W = 32768 = 2^15
  const int tid  = threadIdx.x;
  const int head = tid >> 5;

  const int st = min(max(t_ - 1, 0), Tv - KTv);   // 0..5
  const int sh = min(max(h_ - 3, 0), Hv - KHv);   // 0..57
  const int sw = min(max(w_ - 3, 0), Wv - KWv);   // 0..57

  const float qc = q[(size_t)pos * 128 + tid] * SCALEv;

  float m = -INFINITY, l = 0.f, acc = 0.f;
  const float* rpb_h = rpb + head * (5 * 13 * 13);

  for (int ot = 0; ot < KTv; ++ot) {
    const int ta = st + ot;
    const int rt = ta - t_ + 2;
    const size_t base_t = (size_t)(b * Tv + ta) * Hv;
#pragma unroll
    for (int oh = 0; oh < KHv; ++oh) {
      const int ha = sh + oh;
      const int rh = ha - h_ + 6;
      const size_t base_h = (base_t + ha) * Wv;
      const float* rpb_row = rpb_h + (rt * 13 + rh) * 13 + (sw - w_ + 6);
#pragma unroll
      for (int ow = 0; ow < KWv; ++ow) {
        const size_t kpos = base_h + (sw + ow);
        const float kv = k[kpos * 128 + tid];
        float p = qc * kv;
        // sum across the 32 lanes of this head group (wave64: masks<32 stay in-half)
        p += __shfl_xor(p, 16);
        p += __shfl_xor(p, 8);
        p += __shfl_xor(p, 4);
        p += __shfl_xor(p, 2);
        p += __shfl_xor(p, 1);
        const float s  = p + rpb_row[ow];
        const float mn = fmaxf(m, s);
        const float corr = __expf(m - mn);   // m=-inf first iter -> 0
        const float pe   = __expf(s - mn);
        l   = l * corr + pe;
        acc = acc * corr + pe * v[kpos * 128 + tid];
        m = mn;
      }
    }
  }
  o[(size_t)pos * 128 + tid] = acc / l;
}

// ---------------------------------------------------------------------------
extern "C" void kernel_launch(void* const* d_in, const int* in_sizes, int n_in,
                              void* d_out, int out_size, void* d_ws, size_t ws_size,
                              hipStream_t stream) {
  const float* x      = (const float*)d_in[0];
  const float* y      = (const float*)d_in[1];
  const float* qv_w   = (const float*)d_in[2];
  const float* qv_b   = (const float*)d_in[3];
  const float* k_w    = (const float*)d_in[4];
  const float* k_b    = (const float*)d_in[5];
  const float* proj_w = (const float*)d_in[6];
  const float* proj_b = (const float*)d_in[7];
  const float* rpb    = (const float*)d_in[8];
  float* out = (float*)d_out;

  const size_t elems = (size_t)MPOS * 128;   // 8,388,608
  float* qbuf = (float*)d_ws;                // also reused as attention output
  float* kbuf = qbuf + elems;
  float* vbuf = kbuf + elems;                // total ws use: 100.7 MB

  const int gemm_blocks = MPOS / 32;         // 2048

  gemm_qv  <<<gemm_blocks, 256, 0, stream>>>(x, qv_w, qv_b, qbuf, vbuf);
  gemm_n128<<<gemm_blocks, 256, 0, stream>>>(y, k_w, k_b, kbuf);
  na3d_attn<<<MPOS, 128, 0, stream>>>(qbuf, kbuf, vbuf, rpb, qbuf);
  gemm_n128<<<gemm_blocks, 256, 0, stream>>>(qbuf, proj_w, proj_b, out);
}

// Round 2
// 1268.312 us; speedup vs baseline: 1.4156x; 1.4156x over previous
//
#include <hip/hip_runtime.h>
#include <hip/hip_bf16.h>
#include <cmath>

// Problem constants
#define Bv   2
#define Tv   8
#define Hv   64
#define Wv   64
#define NHv  4
#define MPOS (Bv*Tv*Hv*Wv)           // 65536 positions
#define SCALEv 0.17677669529663687f  // 32^-0.5

// Attention tiling: 8x8 queries (one t, one head) per block.
#define U_H   14
#define U_W   14
#define UPOS  (3*U_H*U_W)            // 588 union K/V positions
#define PSTRIDE 164                  // P row stride (floats); 164%32=4 -> conflict-free
// LDS: region0 = max(Ks 588*64B=37632, P 64*164*4=41984) = 41984; Vs = 37632.
#define VOFF  41984
#define SMEM_BYTES (41984 + 37632)   // 79616 B -> 2 blocks/CU

__device__ __forceinline__ float bf_lo(unsigned u) { return __uint_as_float(u << 16); }
__device__ __forceinline__ float bf_hi(unsigned u) { return __uint_as_float(u & 0xffff0000u); }

// ---------------------------------------------------------------------------
// GEMM A[M,128] @ W[128,256] + bias -> q fp32 (cols 0..127), v bf16 (128..255)
// ---------------------------------------------------------------------------
__global__ __launch_bounds__(256) void gemm_qv(
    const float* __restrict__ x, const float* __restrict__ w,
    const float* __restrict__ bias,
    float* __restrict__ qout, __hip_bfloat16* __restrict__ vout) {
  __shared__ float xs[32][128];
  const int tid  = threadIdx.x;
  const int row0 = blockIdx.x * 32;
  {
    const float4* xg  = (const float4*)(x + (size_t)row0 * 128);
    float4*       xs4 = (float4*)&xs[0][0];
#pragma unroll
    for (int i = 0; i < 4; ++i) xs4[tid + 256 * i] = xg[tid + 256 * i];
  }
  __syncthreads();

  const int cl = tid & 63;
  const int rg = tid >> 6;

  float acc[8][4];
#pragma unroll
  for (int r = 0; r < 8; ++r)
#pragma unroll
    for (int i = 0; i < 4; ++i) acc[r][i] = 0.f;

  for (int k0 = 0; k0 < 128; k0 += 4) {
    float wv[4][4];
#pragma unroll
    for (int j = 0; j < 4; ++j)
#pragma unroll
      for (int i = 0; i < 4; ++i)
        wv[j][i] = w[(k0 + j) * 256 + cl + 64 * i];
#pragma unroll
    for (int r = 0; r < 8; ++r) {
      float4 x4 = *(const float4*)&xs[rg * 8 + r][k0];
#pragma unroll
      for (int i = 0; i < 4; ++i)
        acc[r][i] += x4.x * wv[0][i] + x4.y * wv[1][i] +
                     x4.z * wv[2][i] + x4.w * wv[3][i];
    }
  }

#pragma unroll
  for (int r = 0; r < 8; ++r) {
    const size_t row = row0 + rg * 8 + r;
#pragma unroll
    for (int i = 0; i < 4; ++i) {
      const int col = cl + 64 * i;
      const float val = acc[r][i] + bias[col];
      if (col < 128) qout[row * 128 + col] = val;
      else           vout[row * 128 + (col - 128)] = __float2bfloat16(val);
    }
  }
}

// ---------------------------------------------------------------------------
// GEMM A[M,128] @ W[128,128] + bias -> fp32 out (used for final projection)
// ---------------------------------------------------------------------------
__global__ __launch_bounds__(256) void gemm_n128(
    const float* __restrict__ a, const float* __restrict__ w,
    const float* __restrict__ bias, float* __restrict__ out) {
  __shared__ float xs[32][128];
  const int tid  = threadIdx.x;
  const int row0 = blockIdx.x * 32;
  {
    const float4* xg  = (const float4*)(a + (size_t)row0 * 128);
    float4*       xs4 = (float4*)&xs[0][0];
#pragma unroll
    for (int i = 0; i < 4; ++i) xs4[tid + 256 * i] = xg[tid + 256 * i];
  }
  __syncthreads();

  const int cl = tid & 63;
  const int rg = tid >> 6;

  float acc[8][2];
#pragma unroll
  for (int r = 0; r < 8; ++r) { acc[r][0] = 0.f; acc[r][1] = 0.f; }

  for (int k0 = 0; k0 < 128; k0 += 4) {
    float wv[4][2];
#pragma unroll
    for (int j = 0; j < 4; ++j)
#pragma unroll
      for (int i = 0; i < 2; ++i)
        wv[j][i] = w[(k0 + j) * 128 + cl + 64 * i];
#pragma unroll
    for (int r = 0; r < 8; ++r) {
      float4 x4 = *(const float4*)&xs[rg * 8 + r][k0];
#pragma unroll
      for (int i = 0; i < 2; ++i)
        acc[r][i] += x4.x * wv[0][i] + x4.y * wv[1][i] +
                     x4.z * wv[2][i] + x4.w * wv[3][i];
    }
  }

#pragma unroll
  for (int r = 0; r < 8; ++r) {
    const size_t row = row0 + rg * 8 + r;
#pragma unroll
    for (int i = 0; i < 2; ++i) {
      const int col = cl + 64 * i;
      out[row * 128 + col] = acc[r][i] + bias[col];
    }
  }
}

// Same GEMM but bf16 output (K projection).
__global__ __launch_bounds__(256) void gemm_n128_bf16(
    const float* __restrict__ a, const float* __restrict__ w,
    const float* __restrict__ bias, __hip_bfloat16* __restrict__ out) {
  __shared__ float xs[32][128];
  const int tid  = threadIdx.x;
  const int row0 = blockIdx.x * 32;
  {
    const float4* xg  = (const float4*)(a + (size_t)row0 * 128);
    float4*       xs4 = (float4*)&xs[0][0];
#pragma unroll
    for (int i = 0; i < 4; ++i) xs4[tid + 256 * i] = xg[tid + 256 * i];
  }
  __syncthreads();

  const int cl = tid & 63;
  const int rg = tid >> 6;

  float acc[8][2];
#pragma unroll
  for (int r = 0; r < 8; ++r) { acc[r][0] = 0.f; acc[r][1] = 0.f; }

  for (int k0 = 0; k0 < 128; k0 += 4) {
    float wv[4][2];
#pragma unroll
    for (int j = 0; j < 4; ++j)
#pragma unroll
      for (int i = 0; i < 2; ++i)
        wv[j][i] = w[(k0 + j) * 128 + cl + 64 * i];
#pragma unroll
    for (int r = 0; r < 8; ++r) {
      float4 x4 = *(const float4*)&xs[rg * 8 + r][k0];
#pragma unroll
      for (int i = 0; i < 2; ++i)
        acc[r][i] += x4.x * wv[0][i] + x4.y * wv[1][i] +
                     x4.z * wv[2][i] + x4.w * wv[3][i];
    }
  }

#pragma unroll
  for (int r = 0; r < 8; ++r) {
    const size_t row = row0 + rg * 8 + r;
#pragma unroll
    for (int i = 0; i < 2; ++i) {
      const int col = cl + 64 * i;
      out[row * 128 + col] = __float2bfloat16(acc[r][i] + bias[col]);
    }
  }
}

// ---------------------------------------------------------------------------
// Tiled NA3D attention. Block = 8x8 query tile (one t, one b, one head).
// 512 threads. Stage K/V union window (588 pos x 32ch, bf16) in LDS.
// QK: thread=(q, l8): 19 whole dots from LDS (K xor-swizzled at 16B granule).
// Softmax: 6 shuffles per thread (8-lane groups). P buffer reuses K region.
// AV: thread=(q, dq): accumulate 4 output dims over 147 neighbors.
// oout may alias qin (q rows are block-private; phases barrier-separated).
// ---------------------------------------------------------------------------
__global__ __launch_bounds__(512, 4) void na3d_tile(
    const float* qin,
    const __hip_bfloat16* __restrict__ kin,
    const __hip_bfloat16* __restrict__ vin,
    const float* __restrict__ rpb,
    float* oout) {
  __shared__ __align__(16) unsigned char smem[SMEM_BYTES];
  uint4* Ks = (uint4*)smem;                 // [588][4] uint4, chunk swizzled c^(pos&3)
  uint2* Vs = (uint2*)(smem + VOFF);        // [588][8] uint2 (4 bf16 each)
  float* P  = (float*)smem;                 // [64][PSTRIDE], overlays Ks after QK

  const int tid  = threadIdx.x;
  const int bx   = blockIdx.x;
  const int head = bx & 3;
  const int tile = bx >> 2;
  const int w0 = (tile & 7) << 3;
  const int h0 = ((tile >> 3) & 7) << 3;
  const int t  = (tile >> 6) & 7;
  const int b  = tile >> 9;

  const int st  = min(max(t - 1, 0), Tv - 3);
  const int u_h = min(max(h0 - 3, 0), Hv - U_H);
  const int u_w = min(max(w0 - 3, 0), Wv - U_W);

  // ---- stage K and V (bf16, 16B granules) ----
  for (int i = tid; i < 2 * UPOS * 4; i += 512) {
    const bool isV = (i >= UPOS * 4);
    const int  j   = isV ? i - UPOS * 4 : i;
    const int  pos = j >> 2, c = j & 3;
    const int  ta  = pos / 196;
    const int  r   = pos - ta * 196;
    const int  rh  = r / 14;
    const int  ha  = u_h + rh;
    const int  wa  = u_w + (r - rh * 14);
    const size_t gpos = (((size_t)(b * Tv + st + ta) * Hv + ha) * Wv + wa);
    const uint4* src = (const uint4*)(isV ? (const void*)vin : (const void*)kin);
    const uint4 val = src[gpos * 16 + head * 4 + c];  // row=16 uint4, head slice=4
    if (isV) ((uint4*)Vs)[pos * 4 + c] = val;
    else     Ks[pos * 4 + (c ^ (pos & 3))] = val;
  }

  // ---- per-query constants; load q fragment (overlaps staging) ----
  const int q  = tid >> 3;
  const int l8 = tid & 7;
  const int qh = h0 + (q >> 3);
  const int qw = w0 + (q & 7);
  const int sh = min(max(qh - 3, 0), Hv - 7);
  const int sw = min(max(qw - 3, 0), Wv - 7);
  const int dh = sh - u_h, dw = sw - u_w;
  const size_t qpos = ((size_t)(b * Tv + t) * Hv + qh) * Wv + qw;
  float qf[32];
  {
    const float4* q4 = (const float4*)(qin + qpos * 128 + head * 32);
#pragma unroll
    for (int c = 0; c < 8; ++c) {
      float4 v = q4[c];
      qf[4 * c] = v.x; qf[4 * c + 1] = v.y; qf[4 * c + 2] = v.z; qf[4 * c + 3] = v.w;
    }
  }
  __syncthreads();

  // ---- QK: 19 neighbor dots per thread ----
  const int rt_b = st - t + 2;
  const int rh_b = sh - qh + 6;
  const int rw_b = sw - qw + 6;
  const float* rpb_h = rpb + head * (5 * 13 * 13);

  float s[19];
#pragma unroll
  for (int j = 0; j < 19; ++j) {
    const int n = l8 + 8 * j;
    if (n < 147) {
      const int ot  = n / 49;
      const int rem = n - ot * 49;
      const int oh  = rem / 7;
      const int ow  = rem - oh * 7;
      const int pos = ot * 196 + (dh + oh) * 14 + (dw + ow);
      float acc = 0.f;
#pragma unroll
      for (int c = 0; c < 4; ++c) {
        const uint4 kk = Ks[pos * 4 + (c ^ (pos & 3))];
        acc += bf_lo(kk.x) * qf[8 * c + 0] + bf_hi(kk.x) * qf[8 * c + 1]
             + bf_lo(kk.y) * qf[8 * c + 2] + bf_hi(kk.y) * qf[8 * c + 3]
             + bf_lo(kk.z) * qf[8 * c + 4] + bf_hi(kk.z) * qf[8 * c + 5]
             + bf_lo(kk.w) * qf[8 * c + 6] + bf_hi(kk.w) * qf[8 * c + 7];
      }
      s[j] = acc * SCALEv + rpb_h[(rt_b + ot) * 169 + (rh_b + oh) * 13 + (rw_b + ow)];
    } else {
      s[j] = -1e30f;
    }
  }

  // ---- softmax across the 8-lane group ----
  float mx = s[0];
#pragma unroll
  for (int j = 1; j < 19; ++j) mx = fmaxf(mx, s[j]);
  mx = fmaxf(mx, __shfl_xor(mx, 1));
  mx = fmaxf(mx, __shfl_xor(mx, 2));
  mx = fmaxf(mx, __shfl_xor(mx, 4));
  float sum = 0.f;
#pragma unroll
  for (int j = 0; j < 19; ++j) { s[j] = __expf(s[j] - mx); sum += s[j]; }
  sum += __shfl_xor(sum, 1);
  sum += __shfl_xor(sum, 2);
  sum += __shfl_xor(sum, 4);
  const float inv = 1.0f / sum;

  __syncthreads();   // all Ks reads complete before P overwrites the region
#pragma unroll
  for (int j = 0; j < 19; ++j) P[q * PSTRIDE + l8 + 8 * j] = s[j] * inv;
  __syncthreads();

  // ---- AV: thread=(q, dq) owns output dims dq*4..dq*4+3 ----
  const int dq = l8;
  float4 acc4 = {0.f, 0.f, 0.f, 0.f};
  int n = 0;
#pragma unroll
  for (int ot = 0; ot < 3; ++ot) {
#pragma unroll
    for (int oh = 0; oh < 7; ++oh) {
      const int posr = ot * 196 + (dh + oh) * 14 + dw;
#pragma unroll
      for (int ow = 0; ow < 7; ++ow) {
        const float a = P[q * PSTRIDE + n];
        const uint2 vv = Vs[(posr + ow) * 8 + dq];
        acc4.x += a * bf_lo(vv.x);
        acc4.y += a * bf_hi(vv.x);
        acc4.z += a * bf_lo(vv.y);
        acc4.w += a * bf_hi(vv.y);
        ++n;
      }
    }
  }
  ((float4*)(oout + qpos * 128 + head * 32))[dq] = acc4;
}

// ---------------------------------------------------------------------------
extern "C" void kernel_launch(void* const* d_in, const int* in_sizes, int n_in,
                              void* d_out, int out_size, void* d_ws, size_t ws_size,
                              hipStream_t stream) {
  const float* x      = (const float*)d_in[0];
  const float* y      = (const float*)d_in[1];
  const float* qv_w   = (const float*)d_in[2];
  const float* qv_b   = (const float*)d_in[3];
  const float* k_w    = (const float*)d_in[4];
  const float* k_b    = (const float*)d_in[5];
  const float* proj_w = (const float*)d_in[6];
  const float* proj_b = (const float*)d_in[7];
  const float* rpb    = (const float*)d_in[8];
  float* out = (float*)d_out;

  const size_t elems = (size_t)MPOS * 128;             // 8,388,608
  float*          qbuf = (float*)d_ws;                 // 33.5 MB (q, then attn out in-place)
  __hip_bfloat16* kbuf = (__hip_bfloat16*)(qbuf + elems);   // 16.8 MB
  __hip_bfloat16* vbuf = kbuf + elems;                 // 16.8 MB

  const int gemm_blocks = MPOS / 32;                   // 2048

  gemm_qv       <<<gemm_blocks, 256, 0, stream>>>(x, qv_w, qv_b, qbuf, vbuf);
  gemm_n128_bf16<<<gemm_blocks, 256, 0, stream>>>(y, k_w, k_b, kbuf);
  na3d_tile     <<<4096, 512, 0, stream>>>(qbuf, kbuf, vbuf, rpb, qbuf);
  gemm_n128     <<<gemm_blocks, 256, 0, stream>>>(qbuf, proj_w, proj_b, out);
}

// Round 3
// 835.449 us; speedup vs baseline: 2.1491x; 1.5181x over previous
//
#include <hip/hip_runtime.h>
#include <hip/hip_bf16.h>
#include <cmath>

// Problem constants
#define Bv   2
#define Tv   8
#define Hv   64
#define Wv   64
#define NHv  4
#define MPOS (Bv*Tv*Hv*Wv)           // 65536 positions
#define SCALEv 0.17677669529663687f  // 32^-0.5

// Attention tiling: 8x8 queries (one t, one head) per block.
#define U_H   14
#define U_W   14
#define UPOS  (3*U_H*U_W)            // 588 union K/V positions
#define PSTRIDE 164                  // P row stride (floats); 164%32=4 -> conflict-free
// LDS: region0 = max(Ks 588*64B=37632, P 64*164*4=41984) = 41984; Vs = 37632.
#define VOFF  41984
#define SMEM_BYTES (41984 + 37632)   // 79616 B -> 2 blocks/CU (LDS-capped)

__device__ __forceinline__ float bf_lo(unsigned u) { return __uint_as_float(u << 16); }
__device__ __forceinline__ float bf_hi(unsigned u) { return __uint_as_float(u & 0xffff0000u); }

// ---------------------------------------------------------------------------
// GEMM A[M,128] @ W[128,256] + bias -> q fp32 (cols 0..127), v bf16 (128..255)
// ---------------------------------------------------------------------------
__global__ __launch_bounds__(256) void gemm_qv(
    const float* __restrict__ x, const float* __restrict__ w,
    const float* __restrict__ bias,
    float* __restrict__ qout, __hip_bfloat16* __restrict__ vout) {
  __shared__ float xs[32][128];
  const int tid  = threadIdx.x;
  const int row0 = blockIdx.x * 32;
  {
    const float4* xg  = (const float4*)(x + (size_t)row0 * 128);
    float4*       xs4 = (float4*)&xs[0][0];
#pragma unroll
    for (int i = 0; i < 4; ++i) xs4[tid + 256 * i] = xg[tid + 256 * i];
  }
  __syncthreads();

  const int cl = tid & 63;
  const int rg = tid >> 6;

  float acc[8][4];
#pragma unroll
  for (int r = 0; r < 8; ++r)
#pragma unroll
    for (int i = 0; i < 4; ++i) acc[r][i] = 0.f;

  for (int k0 = 0; k0 < 128; k0 += 4) {
    float wv[4][4];
#pragma unroll
    for (int j = 0; j < 4; ++j)
#pragma unroll
      for (int i = 0; i < 4; ++i)
        wv[j][i] = w[(k0 + j) * 256 + cl + 64 * i];
#pragma unroll
    for (int r = 0; r < 8; ++r) {
      float4 x4 = *(const float4*)&xs[rg * 8 + r][k0];
#pragma unroll
      for (int i = 0; i < 4; ++i)
        acc[r][i] += x4.x * wv[0][i] + x4.y * wv[1][i] +
                     x4.z * wv[2][i] + x4.w * wv[3][i];
    }
  }

#pragma unroll
  for (int r = 0; r < 8; ++r) {
    const size_t row = row0 + rg * 8 + r;
#pragma unroll
    for (int i = 0; i < 4; ++i) {
      const int col = cl + 64 * i;
      const float val = acc[r][i] + bias[col];
      if (col < 128) qout[row * 128 + col] = val;
      else           vout[row * 128 + (col - 128)] = __float2bfloat16(val);
    }
  }
}

// ---------------------------------------------------------------------------
// GEMM A[M,128] @ W[128,128] + bias -> fp32 out (used for final projection)
// ---------------------------------------------------------------------------
__global__ __launch_bounds__(256) void gemm_n128(
    const float* __restrict__ a, const float* __restrict__ w,
    const float* __restrict__ bias, float* __restrict__ out) {
  __shared__ float xs[32][128];
  const int tid  = threadIdx.x;
  const int row0 = blockIdx.x * 32;
  {
    const float4* xg  = (const float4*)(a + (size_t)row0 * 128);
    float4*       xs4 = (float4*)&xs[0][0];
#pragma unroll
    for (int i = 0; i < 4; ++i) xs4[tid + 256 * i] = xg[tid + 256 * i];
  }
  __syncthreads();

  const int cl = tid & 63;
  const int rg = tid >> 6;

  float acc[8][2];
#pragma unroll
  for (int r = 0; r < 8; ++r) { acc[r][0] = 0.f; acc[r][1] = 0.f; }

  for (int k0 = 0; k0 < 128; k0 += 4) {
    float wv[4][2];
#pragma unroll
    for (int j = 0; j < 4; ++j)
#pragma unroll
      for (int i = 0; i < 2; ++i)
        wv[j][i] = w[(k0 + j) * 128 + cl + 64 * i];
#pragma unroll
    for (int r = 0; r < 8; ++r) {
      float4 x4 = *(const float4*)&xs[rg * 8 + r][k0];
#pragma unroll
      for (int i = 0; i < 2; ++i)
        acc[r][i] += x4.x * wv[0][i] + x4.y * wv[1][i] +
                     x4.z * wv[2][i] + x4.w * wv[3][i];
    }
  }

#pragma unroll
  for (int r = 0; r < 8; ++r) {
    const size_t row = row0 + rg * 8 + r;
#pragma unroll
    for (int i = 0; i < 2; ++i) {
      const int col = cl + 64 * i;
      out[row * 128 + col] = acc[r][i] + bias[col];
    }
  }
}

// Same GEMM but bf16 output (K projection).
__global__ __launch_bounds__(256) void gemm_n128_bf16(
    const float* __restrict__ a, const float* __restrict__ w,
    const float* __restrict__ bias, __hip_bfloat16* __restrict__ out) {
  __shared__ float xs[32][128];
  const int tid  = threadIdx.x;
  const int row0 = blockIdx.x * 32;
  {
    const float4* xg  = (const float4*)(a + (size_t)row0 * 128);
    float4*       xs4 = (float4*)&xs[0][0];
#pragma unroll
    for (int i = 0; i < 4; ++i) xs4[tid + 256 * i] = xg[tid + 256 * i];
  }
  __syncthreads();

  const int cl = tid & 63;
  const int rg = tid >> 6;

  float acc[8][2];
#pragma unroll
  for (int r = 0; r < 8; ++r) { acc[r][0] = 0.f; acc[r][1] = 0.f; }

  for (int k0 = 0; k0 < 128; k0 += 4) {
    float wv[4][2];
#pragma unroll
    for (int j = 0; j < 4; ++j)
#pragma unroll
      for (int i = 0; i < 2; ++i)
        wv[j][i] = w[(k0 + j) * 128 + cl + 64 * i];
#pragma unroll
    for (int r = 0; r < 8; ++r) {
      float4 x4 = *(const float4*)&xs[rg * 8 + r][k0];
#pragma unroll
      for (int i = 0; i < 2; ++i)
        acc[r][i] += x4.x * wv[0][i] + x4.y * wv[1][i] +
                     x4.z * wv[2][i] + x4.w * wv[3][i];
    }
  }

#pragma unroll
  for (int r = 0; r < 8; ++r) {
    const size_t row = row0 + rg * 8 + r;
#pragma unroll
    for (int i = 0; i < 2; ++i) {
      const int col = cl + 64 * i;
      out[row * 128 + col] = __float2bfloat16(acc[r][i] + bias[col]);
    }
  }
}

// ---------------------------------------------------------------------------
// Tiled NA3D attention. Block = 8x8 query tile (one t, one b, one head).
// 512 threads. Stage K/V union window (588 pos x 32ch, bf16) in LDS.
// QK: thread=(q, l8): 19 whole dots from LDS (K xor-swizzled at 16B granule).
// Softmax: 6 shuffles per thread (8-lane groups). P buffer reuses K region.
// AV: thread=(q, dq): accumulate 4 output dims over 147 neighbors.
// oout may alias qin (q rows are block-private; phases barrier-separated).
//
// Occupancy: LDS (79.6 KB) caps at 2 blocks/CU = 16 waves. waves_per_eu(2,4)
// lets the allocator use up to 256 VGPRs -> no scratch spills. (R2 lesson:
// __launch_bounds__(512,4) forced a 64-VGPR allocation -> 2.2 GB of scratch
// spill traffic, kernel was spill-latency-bound.)
// ---------------------------------------------------------------------------
__global__ __launch_bounds__(512)
__attribute__((amdgpu_waves_per_eu(2, 4)))
void na3d_tile(
    const float* qin,
    const __hip_bfloat16* __restrict__ kin,
    const __hip_bfloat16* __restrict__ vin,
    const float* __restrict__ rpb,
    float* oout) {
  __shared__ __align__(16) unsigned char smem[SMEM_BYTES];
  uint4* Ks = (uint4*)smem;                 // [588][4] uint4, chunk swizzled c^(pos&3)
  uint2* Vs = (uint2*)(smem + VOFF);        // [588][8] uint2 (4 bf16 each)
  float* P  = (float*)smem;                 // [64][PSTRIDE], overlays Ks after QK

  const int tid  = threadIdx.x;
  const int bx   = blockIdx.x;
  const int head = bx & 3;
  const int tile = bx >> 2;
  const int w0 = (tile & 7) << 3;
  const int h0 = ((tile >> 3) & 7) << 3;
  const int t  = (tile >> 6) & 7;
  const int b  = tile >> 9;

  const int st  = min(max(t - 1, 0), Tv - 3);
  const int u_h = min(max(h0 - 3, 0), Hv - U_H);
  const int u_w = min(max(w0 - 3, 0), Wv - U_W);

  // ---- stage K and V (bf16, 16B granules) ----
  for (int i = tid; i < 2 * UPOS * 4; i += 512) {
    const bool isV = (i >= UPOS * 4);
    const int  j   = isV ? i - UPOS * 4 : i;
    const int  pos = j >> 2, c = j & 3;
    const int  ta  = pos / 196;
    const int  r   = pos - ta * 196;
    const int  rh  = r / 14;
    const int  ha  = u_h + rh;
    const int  wa  = u_w + (r - rh * 14);
    const size_t gpos = (((size_t)(b * Tv + st + ta) * Hv + ha) * Wv + wa);
    const uint4* src = (const uint4*)(isV ? (const void*)vin : (const void*)kin);
    const uint4 val = src[gpos * 16 + head * 4 + c];  // row=16 uint4, head slice=4
    if (isV) ((uint4*)Vs)[pos * 4 + c] = val;
    else     Ks[pos * 4 + (c ^ (pos & 3))] = val;
  }

  // ---- per-query constants; load q fragment (overlaps staging) ----
  const int q  = tid >> 3;
  const int l8 = tid & 7;
  const int qh = h0 + (q >> 3);
  const int qw = w0 + (q & 7);
  const int sh = min(max(qh - 3, 0), Hv - 7);
  const int sw = min(max(qw - 3, 0), Wv - 7);
  const int dh = sh - u_h, dw = sw - u_w;
  const size_t qpos = ((size_t)(b * Tv + t) * Hv + qh) * Wv + qw;
  float qf[32];
  {
    const float4* q4 = (const float4*)(qin + qpos * 128 + head * 32);
#pragma unroll
    for (int c = 0; c < 8; ++c) {
      float4 v = q4[c];
      qf[4 * c] = v.x; qf[4 * c + 1] = v.y; qf[4 * c + 2] = v.z; qf[4 * c + 3] = v.w;
    }
  }
  __syncthreads();

  // ---- QK: 19 neighbor dots per thread ----
  const int rt_b = st - t + 2;
  const int rh_b = sh - qh + 6;
  const int rw_b = sw - qw + 6;
  const float* rpb_h = rpb + head * (5 * 13 * 13);

  float s[19];
#pragma unroll
  for (int j = 0; j < 19; ++j) {
    const int n = l8 + 8 * j;
    if (n < 147) {
      const int ot  = n / 49;
      const int rem = n - ot * 49;
      const int oh  = rem / 7;
      const int ow  = rem - oh * 7;
      const int pos = ot * 196 + (dh + oh) * 14 + (dw + ow);
      float acc = 0.f;
#pragma unroll
      for (int c = 0; c < 4; ++c) {
        const uint4 kk = Ks[pos * 4 + (c ^ (pos & 3))];
        acc += bf_lo(kk.x) * qf[8 * c + 0] + bf_hi(kk.x) * qf[8 * c + 1]
             + bf_lo(kk.y) * qf[8 * c + 2] + bf_hi(kk.y) * qf[8 * c + 3]
             + bf_lo(kk.z) * qf[8 * c + 4] + bf_hi(kk.z) * qf[8 * c + 5]
             + bf_lo(kk.w) * qf[8 * c + 6] + bf_hi(kk.w) * qf[8 * c + 7];
      }
      s[j] = acc * SCALEv + rpb_h[(rt_b + ot) * 169 + (rh_b + oh) * 13 + (rw_b + ow)];
    } else {
      s[j] = -1e30f;
    }
  }

  // ---- softmax across the 8-lane group ----
  float mx = s[0];
#pragma unroll
  for (int j = 1; j < 19; ++j) mx = fmaxf(mx, s[j]);
  mx = fmaxf(mx, __shfl_xor(mx, 1));
  mx = fmaxf(mx, __shfl_xor(mx, 2));
  mx = fmaxf(mx, __shfl_xor(mx, 4));
  float sum = 0.f;
#pragma unroll
  for (int j = 0; j < 19; ++j) { s[j] = __expf(s[j] - mx); sum += s[j]; }
  sum += __shfl_xor(sum, 1);
  sum += __shfl_xor(sum, 2);
  sum += __shfl_xor(sum, 4);
  const float inv = 1.0f / sum;

  __syncthreads();   // all Ks reads complete before P overwrites the region
#pragma unroll
  for (int j = 0; j < 19; ++j) P[q * PSTRIDE + l8 + 8 * j] = s[j] * inv;
  __syncthreads();

  // ---- AV: thread=(q, dq) owns output dims dq*4..dq*4+3 ----
  const int dq = l8;
  float4 acc4 = {0.f, 0.f, 0.f, 0.f};
  int n = 0;
#pragma unroll
  for (int ot = 0; ot < 3; ++ot) {
#pragma unroll
    for (int oh = 0; oh < 7; ++oh) {
      const int posr = ot * 196 + (dh + oh) * 14 + dw;
#pragma unroll
      for (int ow = 0; ow < 7; ++ow) {
        const float a = P[q * PSTRIDE + n];
        const uint2 vv = Vs[(posr + ow) * 8 + dq];
        acc4.x += a * bf_lo(vv.x);
        acc4.y += a * bf_hi(vv.x);
        acc4.z += a * bf_lo(vv.y);
        acc4.w += a * bf_hi(vv.y);
        ++n;
      }
    }
  }
  ((float4*)(oout + qpos * 128 + head * 32))[dq] = acc4;
}

// ---------------------------------------------------------------------------
extern "C" void kernel_launch(void* const* d_in, const int* in_sizes, int n_in,
                              void* d_out, int out_size, void* d_ws, size_t ws_size,
                              hipStream_t stream) {
  const float* x      = (const float*)d_in[0];
  const float* y      = (const float*)d_in[1];
  const float* qv_w   = (const float*)d_in[2];
  const float* qv_b   = (const float*)d_in[3];
  const float* k_w    = (const float*)d_in[4];
  const float* k_b    = (const float*)d_in[5];
  const float* proj_w = (const float*)d_in[6];
  const float* proj_b = (const float*)d_in[7];
  const float* rpb    = (const float*)d_in[8];
  float* out = (float*)d_out;

  const size_t elems = (size_t)MPOS * 128;             // 8,388,608
  float*          qbuf = (float*)d_ws;                 // 33.5 MB (q, then attn out in-place)
  __hip_bfloat16* kbuf = (__hip_bfloat16*)(qbuf + elems);   // 16.8 MB
  __hip_bfloat16* vbuf = kbuf + elems;                 // 16.8 MB

  const int gemm_blocks = MPOS / 32;                   // 2048

  gemm_qv       <<<gemm_blocks, 256, 0, stream>>>(x, qv_w, qv_b, qbuf, vbuf);
  gemm_n128_bf16<<<gemm_blocks, 256, 0, stream>>>(y, k_w, k_b, kbuf);
  na3d_tile     <<<4096, 512, 0, stream>>>(qbuf, kbuf, vbuf, rpb, qbuf);
  gemm_n128     <<<gemm_blocks, 256, 0, stream>>>(qbuf, proj_w, proj_b, out);
}

// Round 4
// 818.225 us; speedup vs baseline: 2.1944x; 1.0211x over previous
//
#include <hip/hip_runtime.h>
#include <hip/hip_bf16.h>
#include <cmath>

// Problem constants
#define Bv   2
#define Tv   8
#define Hv   64
#define Wv   64
#define NHv  4
#define MPOS (Bv*Tv*Hv*Wv)           // 65536 positions
#define SCALEv 0.17677669529663687f  // 32^-0.5

// Attention tiling: 8x8 queries (one t, one head) per block.
#define U_H   14
#define U_W   14
#define UPOS  (3*U_H*U_W)            // 588 union K/V positions
#define PSTRIDE 164                  // P row stride (floats); 164%32=4 -> conflict-free
// LDS: region0 = max(Ks 588*64B=37632, P 64*164*4=41984) = 41984; V = 37632.
#define VOFF  41984
#define SMEM_BYTES (41984 + 37632)   // 79616 B

__device__ __forceinline__ float bf_lo(unsigned u) { return __uint_as_float(u << 16); }
__device__ __forceinline__ float bf_hi(unsigned u) { return __uint_as_float(u & 0xffff0000u); }

// ---------------------------------------------------------------------------
// GEMM A[M,128] @ W[128,256] + bias -> q fp32 (cols 0..127), v bf16 (128..255)
// ---------------------------------------------------------------------------
__global__ __launch_bounds__(256) void gemm_qv(
    const float* __restrict__ x, const float* __restrict__ w,
    const float* __restrict__ bias,
    float* __restrict__ qout, __hip_bfloat16* __restrict__ vout) {
  __shared__ float xs[32][128];
  const int tid  = threadIdx.x;
  const int row0 = blockIdx.x * 32;
  {
    const float4* xg  = (const float4*)(x + (size_t)row0 * 128);
    float4*       xs4 = (float4*)&xs[0][0];
#pragma unroll
    for (int i = 0; i < 4; ++i) xs4[tid + 256 * i] = xg[tid + 256 * i];
  }
  __syncthreads();

  const int cl = tid & 63;
  const int rg = tid >> 6;

  float acc[8][4];
#pragma unroll
  for (int r = 0; r < 8; ++r)
#pragma unroll
    for (int i = 0; i < 4; ++i) acc[r][i] = 0.f;

  for (int k0 = 0; k0 < 128; k0 += 4) {
    float wv[4][4];
#pragma unroll
    for (int j = 0; j < 4; ++j)
#pragma unroll
      for (int i = 0; i < 4; ++i)
        wv[j][i] = w[(k0 + j) * 256 + cl + 64 * i];
#pragma unroll
    for (int r = 0; r < 8; ++r) {
      float4 x4 = *(const float4*)&xs[rg * 8 + r][k0];
#pragma unroll
      for (int i = 0; i < 4; ++i)
        acc[r][i] += x4.x * wv[0][i] + x4.y * wv[1][i] +
                     x4.z * wv[2][i] + x4.w * wv[3][i];
    }
  }

#pragma unroll
  for (int r = 0; r < 8; ++r) {
    const size_t row = row0 + rg * 8 + r;
#pragma unroll
    for (int i = 0; i < 4; ++i) {
      const int col = cl + 64 * i;
      const float val = acc[r][i] + bias[col];
      if (col < 128) qout[row * 128 + col] = val;
      else           vout[row * 128 + (col - 128)] = __float2bfloat16(val);
    }
  }
}

// ---------------------------------------------------------------------------
// GEMM A[M,128] @ W[128,128] + bias -> fp32 out (used for final projection)
// ---------------------------------------------------------------------------
__global__ __launch_bounds__(256) void gemm_n128(
    const float* __restrict__ a, const float* __restrict__ w,
    const float* __restrict__ bias, float* __restrict__ out) {
  __shared__ float xs[32][128];
  const int tid  = threadIdx.x;
  const int row0 = blockIdx.x * 32;
  {
    const float4* xg  = (const float4*)(a + (size_t)row0 * 128);
    float4*       xs4 = (float4*)&xs[0][0];
#pragma unroll
    for (int i = 0; i < 4; ++i) xs4[tid + 256 * i] = xg[tid + 256 * i];
  }
  __syncthreads();

  const int cl = tid & 63;
  const int rg = tid >> 6;

  float acc[8][2];
#pragma unroll
  for (int r = 0; r < 8; ++r) { acc[r][0] = 0.f; acc[r][1] = 0.f; }

  for (int k0 = 0; k0 < 128; k0 += 4) {
    float wv[4][2];
#pragma unroll
    for (int j = 0; j < 4; ++j)
#pragma unroll
      for (int i = 0; i < 2; ++i)
        wv[j][i] = w[(k0 + j) * 128 + cl + 64 * i];
#pragma unroll
    for (int r = 0; r < 8; ++r) {
      float4 x4 = *(const float4*)&xs[rg * 8 + r][k0];
#pragma unroll
      for (int i = 0; i < 2; ++i)
        acc[r][i] += x4.x * wv[0][i] + x4.y * wv[1][i] +
                     x4.z * wv[2][i] + x4.w * wv[3][i];
    }
  }

#pragma unroll
  for (int r = 0; r < 8; ++r) {
    const size_t row = row0 + rg * 8 + r;
#pragma unroll
    for (int i = 0; i < 2; ++i) {
      const int col = cl + 64 * i;
      out[row * 128 + col] = acc[r][i] + bias[col];
    }
  }
}

// Same GEMM but bf16 output (K projection).
__global__ __launch_bounds__(256) void gemm_n128_bf16(
    const float* __restrict__ a, const float* __restrict__ w,
    const float* __restrict__ bias, __hip_bfloat16* __restrict__ out) {
  __shared__ float xs[32][128];
  const int tid  = threadIdx.x;
  const int row0 = blockIdx.x * 32;
  {
    const float4* xg  = (const float4*)(a + (size_t)row0 * 128);
    float4*       xs4 = (float4*)&xs[0][0];
#pragma unroll
    for (int i = 0; i < 4; ++i) xs4[tid + 256 * i] = xg[tid + 256 * i];
  }
  __syncthreads();

  const int cl = tid & 63;
  const int rg = tid >> 6;

  float acc[8][2];
#pragma unroll
  for (int r = 0; r < 8; ++r) { acc[r][0] = 0.f; acc[r][1] = 0.f; }

  for (int k0 = 0; k0 < 128; k0 += 4) {
    float wv[4][2];
#pragma unroll
    for (int j = 0; j < 4; ++j)
#pragma unroll
      for (int i = 0; i < 2; ++i)
        wv[j][i] = w[(k0 + j) * 128 + cl + 64 * i];
#pragma unroll
    for (int r = 0; r < 8; ++r) {
      float4 x4 = *(const float4*)&xs[rg * 8 + r][k0];
#pragma unroll
      for (int i = 0; i < 2; ++i)
        acc[r][i] += x4.x * wv[0][i] + x4.y * wv[1][i] +
                     x4.z * wv[2][i] + x4.w * wv[3][i];
    }
  }

#pragma unroll
  for (int r = 0; r < 8; ++r) {
    const size_t row = row0 + rg * 8 + r;
#pragma unroll
    for (int i = 0; i < 2; ++i) {
      const int col = cl + 64 * i;
      out[row * 128 + col] = __float2bfloat16(acc[r][i] + bias[col]);
    }
  }
}

// ---------------------------------------------------------------------------
// Tiled NA3D attention. Block = 8x8 query tile (one t, one b, one head).
// 512 threads. Stage K/V union window (588 pos x 32ch, bf16) in LDS.
// QK: thread=(q, l8): 19 whole dots from LDS (K xor-swizzled at 16B granule).
// Softmax: 6 shuffles per thread (8-lane groups). P buffer reuses K region.
// AV: thread=(q, dq): accumulate 4 output dims over 147 neighbors.
// V stored TRANSPOSED: Vt[dq][pos] (byte stride 4704 -> bank base 24*dq%32,
// +2*pos) => full wave covers all 32 banks 2-way = conflict-free (m136).
// oout may alias qin (q rows are block-private; phases barrier-separated).
//
// Occupancy: __launch_bounds__(512, 1) -> VGPR cap 512 (block shape forces
// <=256); no scratch spills. R2 lesson: min-waves hint of 4 forced a 128-VGPR
// allocation -> GBs of scratch traffic. LDS 79.6 KB + VGPR>128 -> 1 block/CU;
// the LDS pipe (~15k cyc/block) is the structural floor, not occupancy.
// ---------------------------------------------------------------------------
__global__ __launch_bounds__(512, 1)
void na3d_tile(
    const float* qin,
    const __hip_bfloat16* __restrict__ kin,
    const __hip_bfloat16* __restrict__ vin,
    const float* __restrict__ rpb,
    float* oout) {
  __shared__ __align__(16) unsigned char smem[SMEM_BYTES];
  uint4* Ks = (uint4*)smem;                 // [588][4] uint4, chunk swizzled c^(pos&3)
  uint2* Vt = (uint2*)(smem + VOFF);        // [8][588] uint2 (dq-major, transposed)
  float* P  = (float*)smem;                 // [64][PSTRIDE], overlays Ks after QK

  const int tid  = threadIdx.x;
  const int bx   = blockIdx.x;
  const int head = bx & 3;
  const int tile = bx >> 2;
  const int w0 = (tile & 7) << 3;
  const int h0 = ((tile >> 3) & 7) << 3;
  const int t  = (tile >> 6) & 7;
  const int b  = tile >> 9;

  const int st  = min(max(t - 1, 0), Tv - 3);
  const int u_h = min(max(h0 - 3, 0), Hv - U_H);
  const int u_w = min(max(w0 - 3, 0), Wv - U_W);

  // ---- stage K and V (bf16, 16B global granules) ----
  for (int i = tid; i < 2 * UPOS * 4; i += 512) {
    const bool isV = (i >= UPOS * 4);
    const int  j   = isV ? i - UPOS * 4 : i;
    const int  pos = j >> 2, c = j & 3;
    const int  ta  = pos / 196;
    const int  r   = pos - ta * 196;
    const int  rh  = r / 14;
    const int  ha  = u_h + rh;
    const int  wa  = u_w + (r - rh * 14);
    const size_t gpos = (((size_t)(b * Tv + st + ta) * Hv + ha) * Wv + wa);
    const uint4* src = (const uint4*)(isV ? (const void*)vin : (const void*)kin);
    const uint4 val = src[gpos * 16 + head * 4 + c];  // row=16 uint4, head slice=4
    if (isV) {
      // chunk c holds dims 8c..8c+7 -> dq=2c gets {x,y}, dq=2c+1 gets {z,w}
      Vt[(2 * c)     * UPOS + pos] = make_uint2(val.x, val.y);
      Vt[(2 * c + 1) * UPOS + pos] = make_uint2(val.z, val.w);
    } else {
      Ks[pos * 4 + (c ^ (pos & 3))] = val;
    }
  }

  // ---- per-query constants; load q fragment (overlaps staging) ----
  const int q  = tid >> 3;
  const int l8 = tid & 7;
  const int qh = h0 + (q >> 3);
  const int qw = w0 + (q & 7);
  const int sh = min(max(qh - 3, 0), Hv - 7);
  const int sw = min(max(qw - 3, 0), Wv - 7);
  const int dh = sh - u_h, dw = sw - u_w;
  const size_t qpos = ((size_t)(b * Tv + t) * Hv + qh) * Wv + qw;
  float qf[32];
  {
    const float4* q4 = (const float4*)(qin + qpos * 128 + head * 32);
#pragma unroll
    for (int c = 0; c < 8; ++c) {
      float4 v = q4[c];
      qf[4 * c] = v.x; qf[4 * c + 1] = v.y; qf[4 * c + 2] = v.z; qf[4 * c + 3] = v.w;
    }
  }
  __syncthreads();

  // ---- QK: 19 neighbor dots per thread ----
  const int rt_b = st - t + 2;
  const int rh_b = sh - qh + 6;
  const int rw_b = sw - qw + 6;
  const float* rpb_h = rpb + head * (5 * 13 * 13);

  float s[19];
#pragma unroll
  for (int j = 0; j < 19; ++j) {
    const int n = l8 + 8 * j;
    if (n < 147) {
      const int ot  = n / 49;
      const int rem = n - ot * 49;
      const int oh  = rem / 7;
      const int ow  = rem - oh * 7;
      const int pos = ot * 196 + (dh + oh) * 14 + (dw + ow);
      float acc = 0.f;
#pragma unroll
      for (int c = 0; c < 4; ++c) {
        const uint4 kk = Ks[pos * 4 + (c ^ (pos & 3))];
        acc += bf_lo(kk.x) * qf[8 * c + 0] + bf_hi(kk.x) * qf[8 * c + 1]
             + bf_lo(kk.y) * qf[8 * c + 2] + bf_hi(kk.y) * qf[8 * c + 3]
             + bf_lo(kk.z) * qf[8 * c + 4] + bf_hi(kk.z) * qf[8 * c + 5]
             + bf_lo(kk.w) * qf[8 * c + 6] + bf_hi(kk.w) * qf[8 * c + 7];
      }
      s[j] = acc * SCALEv + rpb_h[(rt_b + ot) * 169 + (rh_b + oh) * 13 + (rw_b + ow)];
    } else {
      s[j] = -1e30f;
    }
  }

  // ---- softmax across the 8-lane group ----
  float mx = s[0];
#pragma unroll
  for (int j = 1; j < 19; ++j) mx = fmaxf(mx, s[j]);
  mx = fmaxf(mx, __shfl_xor(mx, 1));
  mx = fmaxf(mx, __shfl_xor(mx, 2));
  mx = fmaxf(mx, __shfl_xor(mx, 4));
  float sum = 0.f;
#pragma unroll
  for (int j = 0; j < 19; ++j) { s[j] = __expf(s[j] - mx); sum += s[j]; }
  sum += __shfl_xor(sum, 1);
  sum += __shfl_xor(sum, 2);
  sum += __shfl_xor(sum, 4);
  const float inv = 1.0f / sum;

  __syncthreads();   // all Ks reads complete before P overwrites the region
#pragma unroll
  for (int j = 0; j < 19; ++j) P[q * PSTRIDE + l8 + 8 * j] = s[j] * inv;
  __syncthreads();

  // ---- AV: thread=(q, dq) owns output dims dq*4..dq*4+3 ----
  const int dq = l8;
  const uint2* Vq = Vt + dq * UPOS;
  float4 acc4 = {0.f, 0.f, 0.f, 0.f};
  int n = 0;
#pragma unroll
  for (int ot = 0; ot < 3; ++ot) {
#pragma unroll
    for (int oh = 0; oh < 7; ++oh) {
      const int posr = ot * 196 + (dh + oh) * 14 + dw;
#pragma unroll
      for (int ow = 0; ow < 7; ++ow) {
        const float a = P[q * PSTRIDE + n];
        const uint2 vv = Vq[posr + ow];
        acc4.x += a * bf_lo(vv.x);
        acc4.y += a * bf_hi(vv.x);
        acc4.z += a * bf_lo(vv.y);
        acc4.w += a * bf_hi(vv.y);
        ++n;
      }
    }
  }
  ((float4*)(oout + qpos * 128 + head * 32))[dq] = acc4;
}

// ---------------------------------------------------------------------------
extern "C" void kernel_launch(void* const* d_in, const int* in_sizes, int n_in,
                              void* d_out, int out_size, void* d_ws, size_t ws_size,
                              hipStream_t stream) {
  const float* x      = (const float*)d_in[0];
  const float* y      = (const float*)d_in[1];
  const float* qv_w   = (const float*)d_in[2];
  const float* qv_b   = (const float*)d_in[3];
  const float* k_w    = (const float*)d_in[4];
  const float* k_b    = (const float*)d_in[5];
  const float* proj_w = (const float*)d_in[6];
  const float* proj_b = (const float*)d_in[7];
  const float* rpb    = (const float*)d_in[8];
  float* out = (float*)d_out;

  const size_t elems = (size_t)MPOS * 128;             // 8,388,608
  float*          qbuf = (float*)d_ws;                 // 33.5 MB (q, then attn out in-place)
  __hip_bfloat16* kbuf = (__hip_bfloat16*)(qbuf + elems);   // 16.8 MB
  __hip_bfloat16* vbuf = kbuf + elems;                 // 16.8 MB

  const int gemm_blocks = MPOS / 32;                   // 2048

  gemm_qv       <<<gemm_blocks, 256, 0, stream>>>(x, qv_w, qv_b, qbuf, vbuf);
  gemm_n128_bf16<<<gemm_blocks, 256, 0, stream>>>(y, k_w, k_b, kbuf);
  na3d_tile     <<<4096, 512, 0, stream>>>(qbuf, kbuf, vbuf, rpb, qbuf);
  gemm_n128     <<<gemm_blocks, 256, 0, stream>>>(qbuf, proj_w, proj_b, out);
}

// Round 5
// 518.012 us; speedup vs baseline: 3.4661x; 1.5795x over previous
//
#include <hip/hip_runtime.h>
#include <hip/hip_bf16.h>
#include <cmath>

// Problem constants
#define Bv   2
#define Tv   8
#define Hv   64
#define Wv   64
#define NHv  4
#define MPOS (Bv*Tv*Hv*Wv)           // 65536 positions
#define SCALEv 0.17677669529663687f  // 32^-0.5

// Attention tiling: 8x8 queries (one t, one head) per block.
#define U_H   14
#define U_W   14
#define UPOS  (3*U_H*U_W)            // 588 union K/V positions
#define VSTRIDE 594                  // Vt row stride in uint2; 594%16==2 -> bank=(4dq+2pos)%32, uniform
#define PSTRIDE 152                  // P row stride in floats; 152%32==24 -> 2-way (free)
// LDS layout (disjoint): Ks [0,37632) | Vt [37632,75648) | P [75648,114560)
#define VOFF  37632
#define POFF  75648
#define SMEM_BYTES (POFF + 64*PSTRIDE*4)   // 114560 B -> 1 block/CU

__device__ __forceinline__ float bf_lo(unsigned u) { return __uint_as_float(u << 16); }
__device__ __forceinline__ float bf_hi(unsigned u) { return __uint_as_float(u & 0xffff0000u); }

// ---------------------------------------------------------------------------
// GEMM A[M,128] @ W[128,256] + bias -> q fp32 (cols 0..127), v bf16 (128..255)
// ---------------------------------------------------------------------------
__global__ __launch_bounds__(256) void gemm_qv(
    const float* __restrict__ x, const float* __restrict__ w,
    const float* __restrict__ bias,
    float* __restrict__ qout, __hip_bfloat16* __restrict__ vout) {
  __shared__ float xs[32][128];
  const int tid  = threadIdx.x;
  const int row0 = blockIdx.x * 32;
  {
    const float4* xg  = (const float4*)(x + (size_t)row0 * 128);
    float4*       xs4 = (float4*)&xs[0][0];
#pragma unroll
    for (int i = 0; i < 4; ++i) xs4[tid + 256 * i] = xg[tid + 256 * i];
  }
  __syncthreads();

  const int cl = tid & 63;
  const int rg = tid >> 6;

  float acc[8][4];
#pragma unroll
  for (int r = 0; r < 8; ++r)
#pragma unroll
    for (int i = 0; i < 4; ++i) acc[r][i] = 0.f;

  for (int k0 = 0; k0 < 128; k0 += 4) {
    float wv[4][4];
#pragma unroll
    for (int j = 0; j < 4; ++j)
#pragma unroll
      for (int i = 0; i < 4; ++i)
        wv[j][i] = w[(k0 + j) * 256 + cl + 64 * i];
#pragma unroll
    for (int r = 0; r < 8; ++r) {
      float4 x4 = *(const float4*)&xs[rg * 8 + r][k0];
#pragma unroll
      for (int i = 0; i < 4; ++i)
        acc[r][i] += x4.x * wv[0][i] + x4.y * wv[1][i] +
                     x4.z * wv[2][i] + x4.w * wv[3][i];
    }
  }

#pragma unroll
  for (int r = 0; r < 8; ++r) {
    const size_t row = row0 + rg * 8 + r;
#pragma unroll
    for (int i = 0; i < 4; ++i) {
      const int col = cl + 64 * i;
      const float val = acc[r][i] + bias[col];
      if (col < 128) qout[row * 128 + col] = val;
      else           vout[row * 128 + (col - 128)] = __float2bfloat16(val);
    }
  }
}

// ---------------------------------------------------------------------------
// GEMM A[M,128] @ W[128,128] + bias -> fp32 out (final projection)
// ---------------------------------------------------------------------------
__global__ __launch_bounds__(256) void gemm_n128(
    const float* __restrict__ a, const float* __restrict__ w,
    const float* __restrict__ bias, float* __restrict__ out) {
  __shared__ float xs[32][128];
  const int tid  = threadIdx.x;
  const int row0 = blockIdx.x * 32;
  {
    const float4* xg  = (const float4*)(a + (size_t)row0 * 128);
    float4*       xs4 = (float4*)&xs[0][0];
#pragma unroll
    for (int i = 0; i < 4; ++i) xs4[tid + 256 * i] = xg[tid + 256 * i];
  }
  __syncthreads();

  const int cl = tid & 63;
  const int rg = tid >> 6;

  float acc[8][2];
#pragma unroll
  for (int r = 0; r < 8; ++r) { acc[r][0] = 0.f; acc[r][1] = 0.f; }

  for (int k0 = 0; k0 < 128; k0 += 4) {
    float wv[4][2];
#pragma unroll
    for (int j = 0; j < 4; ++j)
#pragma unroll
      for (int i = 0; i < 2; ++i)
        wv[j][i] = w[(k0 + j) * 128 + cl + 64 * i];
#pragma unroll
    for (int r = 0; r < 8; ++r) {
      float4 x4 = *(const float4*)&xs[rg * 8 + r][k0];
#pragma unroll
      for (int i = 0; i < 2; ++i)
        acc[r][i] += x4.x * wv[0][i] + x4.y * wv[1][i] +
                     x4.z * wv[2][i] + x4.w * wv[3][i];
    }
  }

#pragma unroll
  for (int r = 0; r < 8; ++r) {
    const size_t row = row0 + rg * 8 + r;
#pragma unroll
    for (int i = 0; i < 2; ++i) {
      const int col = cl + 64 * i;
      out[row * 128 + col] = acc[r][i] + bias[col];
    }
  }
}

// Same GEMM but bf16 output (K projection).
__global__ __launch_bounds__(256) void gemm_n128_bf16(
    const float* __restrict__ a, const float* __restrict__ w,
    const float* __restrict__ bias, __hip_bfloat16* __restrict__ out) {
  __shared__ float xs[32][128];
  const int tid  = threadIdx.x;
  const int row0 = blockIdx.x * 32;
  {
    const float4* xg  = (const float4*)(a + (size_t)row0 * 128);
    float4*       xs4 = (float4*)&xs[0][0];
#pragma unroll
    for (int i = 0; i < 4; ++i) xs4[tid + 256 * i] = xg[tid + 256 * i];
  }
  __syncthreads();

  const int cl = tid & 63;
  const int rg = tid >> 6;

  float acc[8][2];
#pragma unroll
  for (int r = 0; r < 8; ++r) { acc[r][0] = 0.f; acc[r][1] = 0.f; }

  for (int k0 = 0; k0 < 128; k0 += 4) {
    float wv[4][2];
#pragma unroll
    for (int j = 0; j < 4; ++j)
#pragma unroll
      for (int i = 0; i < 2; ++i)
        wv[j][i] = w[(k0 + j) * 128 + cl + 64 * i];
#pragma unroll
    for (int r = 0; r < 8; ++r) {
      float4 x4 = *(const float4*)&xs[rg * 8 + r][k0];
#pragma unroll
      for (int i = 0; i < 2; ++i)
        acc[r][i] += x4.x * wv[0][i] + x4.y * wv[1][i] +
                     x4.z * wv[2][i] + x4.w * wv[3][i];
    }
  }

#pragma unroll
  for (int r = 0; r < 8; ++r) {
    const size_t row = row0 + rg * 8 + r;
#pragma unroll
    for (int i = 0; i < 2; ++i) {
      const int col = cl + 64 * i;
      out[row * 128 + col] = __float2bfloat16(acc[r][i] + bias[col]);
    }
  }
}

// ---------------------------------------------------------------------------
// Tiled NA3D attention. Block = 8x8 query tile (one t, one b, one head).
// 512 threads. K/V union window (588 pos x 32ch, bf16) staged in LDS.
//
// QK (thread=(q,l8)): 19 whole 32-dim dots from Ks; raw score STREAMED to
//   LDS P immediately (no s[19] register array -> bounded live set, unroll 2
//   caps hoisted ds_reads; R4 lesson: full unroll hoisted 76 b128 loads ->
//   ~300 VGPR demand -> unavoidable scratch spills at any cap).
// Softmax: running max in QK; 3 shfls for group max; pass2 re-reads own 19
//   scores, exp, write back UNNORMALIZED; 3 shfls for sum; AV scales by inv.
// AV (thread=(q,dq)): 4 output dims over 147 neighbors from Vt.
//   Vt[dq][pos] stride 594 uint2: bank=(4dq+2pos)%32 -> uniform 4/bank = b64
//   minimum, conflict-free. P stride 152: all P accesses 2-way or broadcast.
// oout may alias qin (q rows block-private; phases barrier-separated).
// ---------------------------------------------------------------------------
__global__ __launch_bounds__(512, 1)
void na3d_tile(
    const float* qin,
    const __hip_bfloat16* __restrict__ kin,
    const __hip_bfloat16* __restrict__ vin,
    const float* __restrict__ rpb,
    float* oout) {
  __shared__ __align__(16) unsigned char smem[SMEM_BYTES];
  uint4* Ks = (uint4*)smem;                 // [588][4] uint4, chunk swizzled c^(pos&3)
  uint2* Vt = (uint2*)(smem + VOFF);        // [8][594] uint2 (dq-major, padded)
  float* P  = (float*)(smem + POFF);        // [64][PSTRIDE] raw scores -> exp

  const int tid  = threadIdx.x;
  const int bx   = blockIdx.x;
  const int head = bx & 3;
  const int tile = bx >> 2;
  const int w0 = (tile & 7) << 3;
  const int h0 = ((tile >> 3) & 7) << 3;
  const int t  = (tile >> 6) & 7;
  const int b  = tile >> 9;

  const int st  = min(max(t - 1, 0), Tv - 3);
  const int u_h = min(max(h0 - 3, 0), Hv - U_H);
  const int u_w = min(max(w0 - 3, 0), Wv - U_W);

  // ---- stage K and V (bf16, 16B global granules) ----
  for (int i = tid; i < 2 * UPOS * 4; i += 512) {
    const bool isV = (i >= UPOS * 4);
    const int  j   = isV ? i - UPOS * 4 : i;
    const int  pos = j >> 2, c = j & 3;
    const int  ta  = pos / 196;
    const int  r   = pos - ta * 196;
    const int  rh  = r / 14;
    const int  ha  = u_h + rh;
    const int  wa  = u_w + (r - rh * 14);
    const size_t gpos = (((size_t)(b * Tv + st + ta) * Hv + ha) * Wv + wa);
    const uint4* src = (const uint4*)(isV ? (const void*)vin : (const void*)kin);
    const uint4 val = src[gpos * 16 + head * 4 + c];  // row=16 uint4, head slice=4
    if (isV) {
      // chunk c holds dims 8c..8c+7 -> dq=2c gets {x,y}, dq=2c+1 gets {z,w}
      Vt[(2 * c)     * VSTRIDE + pos] = make_uint2(val.x, val.y);
      Vt[(2 * c + 1) * VSTRIDE + pos] = make_uint2(val.z, val.w);
    } else {
      Ks[pos * 4 + (c ^ (pos & 3))] = val;
    }
  }

  // ---- per-query constants; load q fragment (overlaps staging) ----
  const int q  = tid >> 3;
  const int l8 = tid & 7;
  const int qh = h0 + (q >> 3);
  const int qw = w0 + (q & 7);
  const int sh = min(max(qh - 3, 0), Hv - 7);
  const int sw = min(max(qw - 3, 0), Wv - 7);
  const int dh = sh - u_h, dw = sw - u_w;
  const size_t qpos = ((size_t)(b * Tv + t) * Hv + qh) * Wv + qw;
  float qf[32];
  {
    const float4* q4 = (const float4*)(qin + qpos * 128 + head * 32);
#pragma unroll
    for (int c = 0; c < 8; ++c) {
      float4 v = q4[c];
      qf[4 * c] = v.x; qf[4 * c + 1] = v.y; qf[4 * c + 2] = v.z; qf[4 * c + 3] = v.w;
    }
  }
  __syncthreads();

  // ---- QK: 19 neighbor dots per thread, streamed to P ----
  const int rt_b = st - t + 2;
  const int rh_b = sh - qh + 6;
  const int rw_b = sw - qw + 6;
  const float* rpb_h = rpb + head * (5 * 13 * 13);
  float* Pq = P + q * PSTRIDE;

  float mx = -1e30f;
#pragma unroll 2
  for (int j = 0; j < 19; ++j) {
    const int n = l8 + 8 * j;
    float s = -1e30f;
    if (n < 147) {
      const int ot  = n / 49;
      const int rem = n - ot * 49;
      const int oh  = rem / 7;
      const int ow  = rem - oh * 7;
      const int pos = ot * 196 + (dh + oh) * 14 + (dw + ow);
      float acc = 0.f;
#pragma unroll
      for (int c = 0; c < 4; ++c) {
        const uint4 kk = Ks[pos * 4 + (c ^ (pos & 3))];
        acc += bf_lo(kk.x) * qf[8 * c + 0] + bf_hi(kk.x) * qf[8 * c + 1]
             + bf_lo(kk.y) * qf[8 * c + 2] + bf_hi(kk.y) * qf[8 * c + 3]
             + bf_lo(kk.z) * qf[8 * c + 4] + bf_hi(kk.z) * qf[8 * c + 5]
             + bf_lo(kk.w) * qf[8 * c + 6] + bf_hi(kk.w) * qf[8 * c + 7];
      }
      s = acc * SCALEv + rpb_h[(rt_b + ot) * 169 + (rh_b + oh) * 13 + (rw_b + ow)];
    }
    Pq[n] = s;                       // n <= 151 < PSTRIDE
    mx = fmaxf(mx, s);
  }

  // ---- softmax: group max, exp pass (re-read own scores), group sum ----
  mx = fmaxf(mx, __shfl_xor(mx, 1));
  mx = fmaxf(mx, __shfl_xor(mx, 2));
  mx = fmaxf(mx, __shfl_xor(mx, 4));
  float sum = 0.f;
#pragma unroll 2
  for (int j = 0; j < 19; ++j) {
    const int n = l8 + 8 * j;
    const float e = __expf(Pq[n] - mx);   // pad scores (-1e30) -> exp = 0
    sum += e;
    Pq[n] = e;
  }
  sum += __shfl_xor(sum, 1);
  sum += __shfl_xor(sum, 2);
  sum += __shfl_xor(sum, 4);
  const float inv = 1.0f / sum;
  __syncthreads();   // P(exp) visible to all threads of the q-tile

  // ---- AV: thread=(q, dq) owns output dims dq*4..dq*4+3 ----
  const int dq = l8;
  const uint2* Vq = Vt + dq * VSTRIDE;
  float4 acc4 = {0.f, 0.f, 0.f, 0.f};
  int n = 0;
#pragma unroll
  for (int ot = 0; ot < 3; ++ot) {
#pragma unroll
    for (int oh = 0; oh < 7; ++oh) {
      const int posr = ot * 196 + (dh + oh) * 14 + dw;
#pragma unroll
      for (int ow = 0; ow < 7; ++ow) {
        const float a = Pq[n];
        const uint2 vv = Vq[posr + ow];
        acc4.x += a * bf_lo(vv.x);
        acc4.y += a * bf_hi(vv.x);
        acc4.z += a * bf_lo(vv.y);
        acc4.w += a * bf_hi(vv.y);
        ++n;
      }
    }
  }
  acc4.x *= inv; acc4.y *= inv; acc4.z *= inv; acc4.w *= inv;
  ((float4*)(oout + qpos * 128 + head * 32))[dq] = acc4;
}

// ---------------------------------------------------------------------------
extern "C" void kernel_launch(void* const* d_in, const int* in_sizes, int n_in,
                              void* d_out, int out_size, void* d_ws, size_t ws_size,
                              hipStream_t stream) {
  const float* x      = (const float*)d_in[0];
  const float* y      = (const float*)d_in[1];
  const float* qv_w   = (const float*)d_in[2];
  const float* qv_b   = (const float*)d_in[3];
  const float* k_w    = (const float*)d_in[4];
  const float* k_b    = (const float*)d_in[5];
  const float* proj_w = (const float*)d_in[6];
  const float* proj_b = (const float*)d_in[7];
  const float* rpb    = (const float*)d_in[8];
  float* out = (float*)d_out;

  const size_t elems = (size_t)MPOS * 128;             // 8,388,608
  float*          qbuf = (float*)d_ws;                 // 33.5 MB (q, then attn out in-place)
  __hip_bfloat16* kbuf = (__hip_bfloat16*)(qbuf + elems);   // 16.8 MB
  __hip_bfloat16* vbuf = kbuf + elems;                 // 16.8 MB

  const int gemm_blocks = MPOS / 32;                   // 2048

  gemm_qv       <<<gemm_blocks, 256, 0, stream>>>(x, qv_w, qv_b, qbuf, vbuf);
  gemm_n128_bf16<<<gemm_blocks, 256, 0, stream>>>(y, k_w, k_b, kbuf);
  na3d_tile     <<<4096, 512, 0, stream>>>(qbuf, kbuf, vbuf, rpb, qbuf);
  gemm_n128     <<<gemm_blocks, 256, 0, stream>>>(qbuf, proj_w, proj_b, out);
}

// Round 6
// 455.698 us; speedup vs baseline: 3.9401x; 1.1367x over previous
//
#include <hip/hip_runtime.h>
#include <hip/hip_bf16.h>
#include <hip/hip_fp16.h>
#include <cmath>

// Problem constants
#define Bv   2
#define Tv   8
#define Hv   64
#define Wv   64
#define MPOS (Bv*Tv*Hv*Wv)           // 65536 positions
#define SCALEv 0.17677669529663687f  // 32^-0.5

// Attention tiling: 8x8 queries (one t, one b, one head) per block.
#define U_H   14
#define U_W   14
#define UPOS  588                    // 3*14*14 union K/V positions

// LDS layout (bytes). All strides bank-engineered (see comments at use site).
#define KOFF   0                     // Ks: 592 rows x 64 B (u-major, slot-swizzled)
#define VTOFF  37888                 // Vt: 32 rows x 1232 B (d-major bf16, 616 cols)
#define POFF2  77312                 // P : 64 rows x 1264 B (632 f16 -> bf16 in place)
#define LUTOFF 158208                // 640 x 4 B  (u -> packed rpb-idx/uh/uw)
#define SMEM_BYTES 160768            // <= 163840 (160 KiB/CU) -> 1 block/CU

typedef __attribute__((ext_vector_type(8))) short bf16x8;   // MFMA A/B frag (8 bf16)
typedef __attribute__((ext_vector_type(4))) float f32x4;    // MFMA C/D frag

__device__ __forceinline__ unsigned short f2bf16(float x) {
  return __builtin_bit_cast(unsigned short, __float2bfloat16(x));
}
__device__ __forceinline__ float h2f(unsigned short h) {
  return __half2float(__builtin_bit_cast(__half, h));
}
__device__ __forceinline__ unsigned short f2h(float x) {
  return __builtin_bit_cast(unsigned short, __float2half(x));
}

// ---------------------------------------------------------------------------
// GEMM A[M,128] @ W[128,256] + bias -> q fp32 (cols 0..127), v bf16 (128..255)
// ---------------------------------------------------------------------------
__global__ __launch_bounds__(256) void gemm_qv(
    const float* __restrict__ x, const float* __restrict__ w,
    const float* __restrict__ bias,
    float* __restrict__ qout, __hip_bfloat16* __restrict__ vout) {
  __shared__ float xs[32][128];
  const int tid  = threadIdx.x;
  const int row0 = blockIdx.x * 32;
  {
    const float4* xg  = (const float4*)(x + (size_t)row0 * 128);
    float4*       xs4 = (float4*)&xs[0][0];
#pragma unroll
    for (int i = 0; i < 4; ++i) xs4[tid + 256 * i] = xg[tid + 256 * i];
  }
  __syncthreads();

  const int cl = tid & 63;
  const int rg = tid >> 6;

  float acc[8][4];
#pragma unroll
  for (int r = 0; r < 8; ++r)
#pragma unroll
    for (int i = 0; i < 4; ++i) acc[r][i] = 0.f;

  for (int k0 = 0; k0 < 128; k0 += 4) {
    float wv[4][4];
#pragma unroll
    for (int j = 0; j < 4; ++j)
#pragma unroll
      for (int i = 0; i < 4; ++i)
        wv[j][i] = w[(k0 + j) * 256 + cl + 64 * i];
#pragma unroll
    for (int r = 0; r < 8; ++r) {
      float4 x4 = *(const float4*)&xs[rg * 8 + r][k0];
#pragma unroll
      for (int i = 0; i < 4; ++i)
        acc[r][i] += x4.x * wv[0][i] + x4.y * wv[1][i] +
                     x4.z * wv[2][i] + x4.w * wv[3][i];
    }
  }

#pragma unroll
  for (int r = 0; r < 8; ++r) {
    const size_t row = row0 + rg * 8 + r;
#pragma unroll
    for (int i = 0; i < 4; ++i) {
      const int col = cl + 64 * i;
      const float val = acc[r][i] + bias[col];
      if (col < 128) qout[row * 128 + col] = val;
      else           vout[row * 128 + (col - 128)] = __float2bfloat16(val);
    }
  }
}

// ---------------------------------------------------------------------------
// GEMM A[M,128] @ W[128,128] + bias -> fp32 out (final projection)
// ---------------------------------------------------------------------------
__global__ __launch_bounds__(256) void gemm_n128(
    const float* __restrict__ a, const float* __restrict__ w,
    const float* __restrict__ bias, float* __restrict__ out) {
  __shared__ float xs[32][128];
  const int tid  = threadIdx.x;
  const int row0 = blockIdx.x * 32;
  {
    const float4* xg  = (const float4*)(a + (size_t)row0 * 128);
    float4*       xs4 = (float4*)&xs[0][0];
#pragma unroll
    for (int i = 0; i < 4; ++i) xs4[tid + 256 * i] = xg[tid + 256 * i];
  }
  __syncthreads();

  const int cl = tid & 63;
  const int rg = tid >> 6;

  float acc[8][2];
#pragma unroll
  for (int r = 0; r < 8; ++r) { acc[r][0] = 0.f; acc[r][1] = 0.f; }

  for (int k0 = 0; k0 < 128; k0 += 4) {
    float wv[4][2];
#pragma unroll
    for (int j = 0; j < 4; ++j)
#pragma unroll
      for (int i = 0; i < 2; ++i)
        wv[j][i] = w[(k0 + j) * 128 + cl + 64 * i];
#pragma unroll
    for (int r = 0; r < 8; ++r) {
      float4 x4 = *(const float4*)&xs[rg * 8 + r][k0];
#pragma unroll
      for (int i = 0; i < 2; ++i)
        acc[r][i] += x4.x * wv[0][i] + x4.y * wv[1][i] +
                     x4.z * wv[2][i] + x4.w * wv[3][i];
    }
  }

#pragma unroll
  for (int r = 0; r < 8; ++r) {
    const size_t row = row0 + rg * 8 + r;
#pragma unroll
    for (int i = 0; i < 2; ++i) {
      const int col = cl + 64 * i;
      out[row * 128 + col] = acc[r][i] + bias[col];
    }
  }
}

// Same GEMM but bf16 output (K projection).
__global__ __launch_bounds__(256) void gemm_n128_bf16(
    const float* __restrict__ a, const float* __restrict__ w,
    const float* __restrict__ bias, __hip_bfloat16* __restrict__ out) {
  __shared__ float xs[32][128];
  const int tid  = threadIdx.x;
  const int row0 = blockIdx.x * 32;
  {
    const float4* xg  = (const float4*)(a + (size_t)row0 * 128);
    float4*       xs4 = (float4*)&xs[0][0];
#pragma unroll
    for (int i = 0; i < 4; ++i) xs4[tid + 256 * i] = xg[tid + 256 * i];
  }
  __syncthreads();

  const int cl = tid & 63;
  const int rg = tid >> 6;

  float acc[8][2];
#pragma unroll
  for (int r = 0; r < 8; ++r) { acc[r][0] = 0.f; acc[r][1] = 0.f; }

  for (int k0 = 0; k0 < 128; k0 += 4) {
    float wv[4][2];
#pragma unroll
    for (int j = 0; j < 4; ++j)
#pragma unroll
      for (int i = 0; i < 2; ++i)
        wv[j][i] = w[(k0 + j) * 128 + cl + 64 * i];
#pragma unroll
    for (int r = 0; r < 8; ++r) {
      float4 x4 = *(const float4*)&xs[rg * 8 + r][k0];
#pragma unroll
      for (int i = 0; i < 2; ++i)
        acc[r][i] += x4.x * wv[0][i] + x4.y * wv[1][i] +
                     x4.z * wv[2][i] + x4.w * wv[3][i];
    }
  }

#pragma unroll
  for (int r = 0; r < 8; ++r) {
    const size_t row = row0 + rg * 8 + r;
#pragma unroll
    for (int i = 0; i < 2; ++i) {
      const int col = cl + 64 * i;
      out[row * 128 + col] = __float2bfloat16(acc[r][i] + bias[col]);
    }
  }
}

// ---------------------------------------------------------------------------
// MFMA NA3D attention (union-GEMM / NATTEN style). Block = 8x8 query tile
// (one b,t,head), 512 threads = 8 waves.
//
// Phase 1 (stage):  K union window -> Ks[u][32d] bf16 (64B rows, chunk slot
//   swizzled (c+(u>>2))&3 so QK B-frag b128 reads hit 8 distinct bank-groups
//   = conflict-free); V -> Vt[d][u] transposed (1232B rows, 77 odd*16B -> AV
//   B-frag conflict-free); LUT[u] = packed (rpb partial idx | uh | uw).
// Phase 2 (QK):     S[64x592] = Q*K^T via mfma_f32_16x16x32_bf16 (K=32 = HD
//   in ONE mfma). 4 m-tiles x 37 n-tiles; wave w: mtile=w&3, ntiles (w>>2)+2j.
//   A-frag loaded from global q (fp32 -> bf16, SCALE folded in). Raw scores
//   stored f16 to P (1264B rows, 79 odd*16B -> all P access conflict-free).
// Phase 3 (softmax): thread=(q,l8) processes 10 b128 chunks of P row q:
//   bias+mask (geometry via LUT; invalid -> -inf), exp WITHOUT max-subtract
//   (|s|<~2, overflow impossible), sum via 3 shfls; write bf16 exp in place;
//   inv[q]=1/sum -> dead Ks region.
// Phase 4 (AV):     O[64x32] = P*V, 4m x 2n x 19k mfmas; epilogue scales by
//   inv[q], coalesced fp32 stores. oout may alias qin (q read only in phase 2,
//   each block touches only its own rows/head slice).
// ---------------------------------------------------------------------------
__global__ __launch_bounds__(512, 1)
void na3d_tile(
    const float* qin,
    const __hip_bfloat16* __restrict__ kin,
    const __hip_bfloat16* __restrict__ vin,
    const float* __restrict__ rpb,
    float* oout) {
  __shared__ __align__(16) unsigned char smem[SMEM_BYTES];

  const int tid  = threadIdx.x;
  const int wv   = tid >> 6;
  const int lane = tid & 63;
  const int quad = lane >> 4;
  const int l16  = lane & 15;

  const int bx   = blockIdx.x;
  const int head = bx & 3;
  const int tile = bx >> 2;
  const int w0 = (tile & 7) << 3;
  const int h0 = ((tile >> 3) & 7) << 3;
  const int t  = (tile >> 6) & 7;
  const int b  = tile >> 9;

  const int st  = min(max(t - 1, 0), Tv - 3);
  const int u_h = min(max(h0 - 3, 0), Hv - U_H);
  const int u_w = min(max(w0 - 3, 0), Wv - U_W);
  const int rt_b = st - t + 2;   // 0..2

  // ---- Phase 1: stage K (swizzled), V (transposed), pads, LUT ----
  for (int i = tid; i < 2 * UPOS * 4; i += 512) {
    const bool isV = (i >= UPOS * 4);
    const int  j   = isV ? i - UPOS * 4 : i;
    const int  pos = j >> 2, c = j & 3;
    const int  ta  = pos / 196;
    const int  r   = pos - ta * 196;
    const int  rh  = r / 14;
    const int  ha  = u_h + rh;
    const int  wa  = u_w + (r - rh * 14);
    const size_t gpos = (((size_t)(b * Tv + st + ta) * Hv + ha) * Wv + wa);
    const uint4* src = (const uint4*)(isV ? (const void*)vin : (const void*)kin);
    const uint4 val = src[gpos * 16 + head * 4 + c];   // 16B = 8 bf16 = dims 8c..8c+7
    if (isV) {
      ushort* vt = (ushort*)(smem + VTOFF);
      unsigned vals[4] = {val.x, val.y, val.z, val.w};
#pragma unroll
      for (int m2 = 0; m2 < 4; ++m2) {
        const int d0 = 8 * c + 2 * m2;
        vt[(size_t)d0 * 616 + pos]       = (ushort)(vals[m2] & 0xffffu);
        vt[(size_t)(d0 + 1) * 616 + pos] = (ushort)(vals[m2] >> 16);
      }
    } else {
      const int slot = (c + (pos >> 2)) & 3;
      *(uint4*)(smem + KOFF + pos * 64 + slot * 16) = val;
    }
  }
  // Vt zero pad u in [588,616) for all 32 d (AV k-tiles read u<608; 0*x=0)
  if (tid < 448) {
    const int d = tid / 14, jj = tid - d * 14;
    *(unsigned*)(smem + VTOFF + d * 1232 + 1176 + jj * 4) = 0u;
  }
  // LUT[u] for u in [0,640): f = ut*169+uh*13+uw (partial rpb idx), uh, uw
  for (int u = tid; u < 640; u += 512) {
    const int ut = (u >= 196) + (u >= 392) + (u >= 588);
    const int r2 = u - ut * 196;
    const int uh = r2 / 14;
    const int uw = r2 - uh * 14;
    const int f  = ut * 169 + uh * 13 + uw;
    ((unsigned*)(smem + LUTOFF))[u] =
        (unsigned)f | ((unsigned)uh << 16) | ((unsigned)uw << 24);
  }

  // A-frag (overlaps staging; global read, no LDS dependency):
  // wave's QK m-tile = wv&3; lane row q = mtile*16+l16; k = quad*8+j.
  const int mtile = wv & 3;
  bf16x8 afrag;
  {
    const int q_a  = mtile * 16 + l16;
    const int qh_a = h0 + (q_a >> 3), qw_a = w0 + (q_a & 7);
    const size_t qpos_a = ((size_t)(b * Tv + t) * Hv + qh_a) * Wv + qw_a;
    const float* qp = qin + qpos_a * 128 + head * 32 + quad * 8;
    const float4 qa = *(const float4*)qp;
    const float4 qb = *(const float4*)(qp + 4);
    afrag[0] = (short)f2bf16(qa.x * SCALEv);
    afrag[1] = (short)f2bf16(qa.y * SCALEv);
    afrag[2] = (short)f2bf16(qa.z * SCALEv);
    afrag[3] = (short)f2bf16(qa.w * SCALEv);
    afrag[4] = (short)f2bf16(qb.x * SCALEv);
    afrag[5] = (short)f2bf16(qb.y * SCALEv);
    afrag[6] = (short)f2bf16(qb.z * SCALEv);
    afrag[7] = (short)f2bf16(qb.w * SCALEv);
  }
  __syncthreads();

  // ---- Phase 2: QK MFMAs, raw f16 scores -> P ----
  {
    ushort* ph = (ushort*)(smem + POFF2);
    for (int nt = (wv >> 2); nt < 37; nt += 2) {
      const int u = nt * 16 + l16;
      const int slot = (quad + (u >> 2)) & 3;
      const bf16x8 bfrag = *(const bf16x8*)(smem + KOFF + u * 64 + slot * 16);
      f32x4 c = {0.f, 0.f, 0.f, 0.f};
      c = __builtin_amdgcn_mfma_f32_16x16x32_bf16(afrag, bfrag, c, 0, 0, 0);
#pragma unroll
      for (int r2 = 0; r2 < 4; ++r2) {
        const int qrow = mtile * 16 + quad * 4 + r2;
        ph[(size_t)qrow * 632 + u] = f2h(c[r2]);
      }
    }
  }
  __syncthreads();

  // ---- Phase 3: softmax (bias+mask+exp, no max-subtract) ----
  {
    const int qs  = tid >> 3, l8s = tid & 7;
    const int qh_s = h0 + (qs >> 3), qw_s = w0 + (qs & 7);
    const int sh_s = min(max(qh_s - 3, 0), Hv - 7);
    const int sw_s = min(max(qw_s - 3, 0), Wv - 7);
    const int dh_s = sh_s - u_h, dw_s = sw_s - u_w;
    const int Cq = rt_b * 169 + (u_h - qh_s + 6) * 13 + (u_w - qw_s + 6);
    const float* rpb_h = rpb + head * 845;
    unsigned char* Prow = smem + POFF2 + (size_t)qs * 1264;
    const unsigned* LUT = (const unsigned*)(smem + LUTOFF);

    float sum = 0.f;
#pragma unroll
    for (int jc = 0; jc < 10; ++jc) {
      const int cidx = l8s + 8 * jc;    // b128 chunk within row (79 chunks)
      if (cidx < 79) {
        const int u0 = cidx * 8;
        uint4 pv = *(uint4*)(Prow + cidx * 16);
        const uint4 l0 = *(const uint4*)(LUT + u0);
        const uint4 l1 = *(const uint4*)(LUT + u0 + 4);
        unsigned pw[4] = {pv.x, pv.y, pv.z, pv.w};
        const unsigned lu[8] = {l0.x, l0.y, l0.z, l0.w, l1.x, l1.y, l1.z, l1.w};
#pragma unroll
        for (int e = 0; e < 8; ++e) {
          const unsigned lut = lu[e];
          const int uh = (lut >> 16) & 0xff;
          const int uw = lut >> 24;
          const bool valid = ((unsigned)(uh - dh_s) < 7u) &
                             ((unsigned)(uw - dw_s) < 7u) &
                             (u0 + e < UPOS);
          int idx = (int)(lut & 0xffffu) + Cq;
          idx = min(max(idx, 0), 844);
          const float bias = rpb_h[idx];
          const unsigned short hraw =
              (e & 1) ? (unsigned short)(pw[e >> 1] >> 16)
                      : (unsigned short)(pw[e >> 1] & 0xffffu);
          float s = h2f(hraw) + bias;
          s = valid ? s : -INFINITY;
          const float ex = __expf(s);   // exp(-inf)=0 kills invalid & garbage
          sum += ex;
          const unsigned short ob = f2bf16(ex);
          if (e & 1) pw[e >> 1] = (pw[e >> 1] & 0x0000ffffu) | ((unsigned)ob << 16);
          else       pw[e >> 1] = (pw[e >> 1] & 0xffff0000u) | (unsigned)ob;
        }
        pv.x = pw[0]; pv.y = pw[1]; pv.z = pw[2]; pv.w = pw[3];
        *(uint4*)(Prow + cidx * 16) = pv;   // bf16 exp, in place
      }
    }
    sum += __shfl_xor(sum, 1);
    sum += __shfl_xor(sum, 2);
    sum += __shfl_xor(sum, 4);
    if (l8s == 0) ((float*)(smem + KOFF))[qs] = 1.0f / sum;  // Ks region dead
  }
  __syncthreads();

  // ---- Phase 4: AV MFMAs + scaled store ----
  {
    const int mtA = wv >> 1, ntA = wv & 1;
    const int dcol = ntA * 16 + l16;
    const unsigned char* Abase = smem + POFF2 + (size_t)(mtA * 16 + l16) * 1264;
    const unsigned char* Bbase = smem + VTOFF + (size_t)dcol * 1232;
    f32x4 o = {0.f, 0.f, 0.f, 0.f};
#pragma unroll 4
    for (int kt = 0; kt < 19; ++kt) {
      const bf16x8 a  = *(const bf16x8*)(Abase + kt * 64 + quad * 16);
      const bf16x8 bb = *(const bf16x8*)(Bbase + kt * 64 + quad * 16);
      o = __builtin_amdgcn_mfma_f32_16x16x32_bf16(a, bb, o, 0, 0, 0);
    }
    const float* invArr = (const float*)(smem + KOFF);
#pragma unroll
    for (int r2 = 0; r2 < 4; ++r2) {
      const int qrow = mtA * 16 + quad * 4 + r2;
      const float val = o[r2] * invArr[qrow];
      const int qh2 = h0 + (qrow >> 3), qw2 = w0 + (qrow & 7);
      const size_t qp2 = ((size_t)(b * Tv + t) * Hv + qh2) * Wv + qw2;
      oout[qp2 * 128 + head * 32 + dcol] = val;
    }
  }
}

// ---------------------------------------------------------------------------
extern "C" void kernel_launch(void* const* d_in, const int* in_sizes, int n_in,
                              void* d_out, int out_size, void* d_ws, size_t ws_size,
                              hipStream_t stream) {
  const float* x      = (const float*)d_in[0];
  const float* y      = (const float*)d_in[1];
  const float* qv_w   = (const float*)d_in[2];
  const float* qv_b   = (const float*)d_in[3];
  const float* k_w    = (const float*)d_in[4];
  const float* k_b    = (const float*)d_in[5];
  const float* proj_w = (const float*)d_in[6];
  const float* proj_b = (const float*)d_in[7];
  const float* rpb    = (const float*)d_in[8];
  float* out = (float*)d_out;

  const size_t elems = (size_t)MPOS * 128;             // 8,388,608
  float*          qbuf = (float*)d_ws;                 // 33.5 MB (q, then attn out in-place)
  __hip_bfloat16* kbuf = (__hip_bfloat16*)(qbuf + elems);   // 16.8 MB
  __hip_bfloat16* vbuf = kbuf + elems;                 // 16.8 MB

  const int gemm_blocks = MPOS / 32;                   // 2048

  gemm_qv       <<<gemm_blocks, 256, 0, stream>>>(x, qv_w, qv_b, qbuf, vbuf);
  gemm_n128_bf16<<<gemm_blocks, 256, 0, stream>>>(y, k_w, k_b, kbuf);
  na3d_tile     <<<4096, 512, 0, stream>>>(qbuf, kbuf, vbuf, rpb, qbuf);
  gemm_n128     <<<gemm_blocks, 256, 0, stream>>>(qbuf, proj_w, proj_b, out);
}

// Round 7
// 377.176 us; speedup vs baseline: 4.7603x; 1.2082x over previous
//
#include <hip/hip_runtime.h>
#include <hip/hip_bf16.h>
#include <hip/hip_fp16.h>
#include <cmath>

// Problem constants
#define Bv   2
#define Tv   8
#define Hv   64
#define Wv   64
#define MPOS (Bv*Tv*Hv*Wv)           // 65536 positions
#define SCALEv 0.17677669529663687f  // 32^-0.5

// Attention tiling: 8x8 queries (one t, one b, one head) per block.
#define U_H   14
#define U_W   14
#define UPOS  588                    // 3*14*14 union K/V positions

// Attention LDS layout (bytes); bank-engineered (see R6 comments).
#define KOFF   0                     // Ks: 592 rows x 64 B (u-major, slot-swizzled)
#define VTOFF  37888                 // Vt: 32 rows x 1232 B (d-major bf16, 616 cols)
#define POFF2  77312                 // P : 64 rows x 1264 B (632 f16 -> bf16 in place)
#define LUTOFF 158208                // 640 x 4 B  (u -> packed rpb-idx/uh/uw)
#define SMEM_BYTES 160768            // <= 163840 -> 1 block/CU

// GEMM LDS row padding: 136 bf16 = 272 B; 272/4 = 68 dwords == 4 (mod 32)
// -> b128 frag reads map lanes to bank-group (l16+quad)%8, 8 lanes/group
// = conflict-free optimal (m136).
#define KPAD 136

typedef __attribute__((ext_vector_type(8))) short bf16x8;   // MFMA A/B frag
typedef __attribute__((ext_vector_type(4))) float f32x4;    // MFMA C/D frag

__device__ __forceinline__ unsigned short f2bf16(float x) {
  return __builtin_bit_cast(unsigned short, __float2bfloat16(x));
}
__device__ __forceinline__ float bf2f(unsigned short h) {
  return __uint_as_float((unsigned)h << 16);
}
__device__ __forceinline__ float h2f(unsigned short h) {
  return __half2float(__builtin_bit_cast(__half, h));
}
__device__ __forceinline__ unsigned short f2h(float x) {
  return __builtin_bit_cast(unsigned short, __float2half(x));
}
__device__ __forceinline__ unsigned pk2(float a, float b) {
  return (unsigned)f2bf16(a) | ((unsigned)f2bf16(b) << 16);
}

// ---------------------------------------------------------------------------
// Preconvert weights: transpose to [n][k] bf16 with KPAD row stride.
// proj_w additionally split hi/lo for the bf16x3 fp32-accurate GEMM.
// 65536 flat slots over grid 256x256.
// ---------------------------------------------------------------------------
__global__ __launch_bounds__(256) void preconvert(
    const float* __restrict__ qv_w, const float* __restrict__ k_w,
    const float* __restrict__ proj_w,
    ushort* __restrict__ wqvT, ushort* __restrict__ wkT,
    ushort* __restrict__ wpT_hi, ushort* __restrict__ wpT_lo) {
  const int id = blockIdx.x * 256 + threadIdx.x;
  if (id < 32768) {                       // qv: n<256, k<128
    const int n = id >> 7, kk = id & 127;
    wqvT[n * KPAD + kk] = f2bf16(qv_w[kk * 256 + n]);
  } else if (id < 49152) {                // k: n<128
    const int j = id - 32768;
    const int n = j >> 7, kk = j & 127;
    wkT[n * KPAD + kk] = f2bf16(k_w[kk * 128 + n]);
  } else {                                // proj: hi/lo split
    const int j = id - 49152;
    const int n = j >> 7, kk = j & 127;
    const float v = proj_w[kk * 128 + n];
    const unsigned short hi = f2bf16(v);
    wpT_hi[n * KPAD + kk] = hi;
    wpT_lo[n * KPAD + kk] = f2bf16(v - bf2f(hi));
  }
}

// ---------------------------------------------------------------------------
// MFMA GEMM: qv projection. C[64m x 256n] per block; q = cols 0..127 scaled
// by SCALE -> bf16 qout; v = cols 128..255 -> bf16 vout. 256 thr = 4 waves,
// wave wv owns m-strip wv*16; 16 n-tiles x 4 k-steps = 64 mfma/wave.
// ---------------------------------------------------------------------------
__global__ __launch_bounds__(256) void gemm_qv_mfma(
    const float* __restrict__ x, const ushort* __restrict__ wqvT,
    const float* __restrict__ qv_b,
    ushort* __restrict__ qout, ushort* __restrict__ vout) {
  __shared__ ushort As[64 * KPAD];
  __shared__ ushort Ws[256 * KPAD];
  const int tid  = threadIdx.x;
  const int row0 = blockIdx.x * 64;

  // stage A: 64x128 fp32 -> bf16. thread: row tid/4, cols (tid&3)*32..+31
  {
    const int r = tid >> 2, cb = (tid & 3) * 32;
    const float4* xg = (const float4*)(x + (size_t)(row0 + r) * 128 + cb);
    uint4* dst = (uint4*)(As + r * KPAD + cb);
#pragma unroll
    for (int i = 0; i < 4; ++i) {
      const float4 a = xg[2 * i], b2 = xg[2 * i + 1];
      dst[i] = make_uint4(pk2(a.x, a.y), pk2(a.z, a.w),
                          pk2(b2.x, b2.y), pk2(b2.z, b2.w));
    }
  }
  // stage W: 256*136 ushorts = 4352 uint4
  {
    const uint4* wg = (const uint4*)wqvT;
    uint4* wsv = (uint4*)Ws;
    for (int i = tid; i < 4352; i += 256) wsv[i] = wg[i];
  }
  __syncthreads();

  const int wv = tid >> 6, lane = tid & 63, quad = lane >> 4, l16 = lane & 15;
  f32x4 C[16];
#pragma unroll
  for (int nt = 0; nt < 16; ++nt) C[nt] = (f32x4){0.f, 0.f, 0.f, 0.f};

#pragma unroll
  for (int kk = 0; kk < 4; ++kk) {
    const bf16x8 a = *(const bf16x8*)(As + (wv * 16 + l16) * KPAD + kk * 32 + quad * 8);
#pragma unroll
    for (int nt = 0; nt < 16; ++nt) {
      const bf16x8 b2 = *(const bf16x8*)(Ws + (nt * 16 + l16) * KPAD + kk * 32 + quad * 8);
      C[nt] = __builtin_amdgcn_mfma_f32_16x16x32_bf16(a, b2, C[nt], 0, 0, 0);
    }
  }

#pragma unroll
  for (int nt = 0; nt < 16; ++nt) {
    const int col = nt * 16 + l16;
    const float bias = qv_b[col];
#pragma unroll
    for (int r2 = 0; r2 < 4; ++r2) {
      const size_t row = row0 + wv * 16 + quad * 4 + r2;
      const float val = C[nt][r2] + bias;
      if (col < 128) qout[row * 128 + col] = f2bf16(val * SCALEv);
      else           vout[row * 128 + (col - 128)] = f2bf16(val);
    }
  }
}

// ---------------------------------------------------------------------------
// MFMA GEMM: k projection. C[64m x 128n]; bf16 out.
// ---------------------------------------------------------------------------
__global__ __launch_bounds__(256) void gemm_k_mfma(
    const float* __restrict__ y, const ushort* __restrict__ wkT,
    const float* __restrict__ k_b, ushort* __restrict__ kout) {
  __shared__ ushort As[64 * KPAD];
  __shared__ ushort Ws[128 * KPAD];
  const int tid  = threadIdx.x;
  const int row0 = blockIdx.x * 64;
  {
    const int r = tid >> 2, cb = (tid & 3) * 32;
    const float4* xg = (const float4*)(y + (size_t)(row0 + r) * 128 + cb);
    uint4* dst = (uint4*)(As + r * KPAD + cb);
#pragma unroll
    for (int i = 0; i < 4; ++i) {
      const float4 a = xg[2 * i], b2 = xg[2 * i + 1];
      dst[i] = make_uint4(pk2(a.x, a.y), pk2(a.z, a.w),
                          pk2(b2.x, b2.y), pk2(b2.z, b2.w));
    }
  }
  {
    const uint4* wg = (const uint4*)wkT;
    uint4* wsv = (uint4*)Ws;
    for (int i = tid; i < 2176; i += 256) wsv[i] = wg[i];
  }
  __syncthreads();

  const int wv = tid >> 6, lane = tid & 63, quad = lane >> 4, l16 = lane & 15;
  f32x4 C[8];
#pragma unroll
  for (int nt = 0; nt < 8; ++nt) C[nt] = (f32x4){0.f, 0.f, 0.f, 0.f};

#pragma unroll
  for (int kk = 0; kk < 4; ++kk) {
    const bf16x8 a = *(const bf16x8*)(As + (wv * 16 + l16) * KPAD + kk * 32 + quad * 8);
#pragma unroll
    for (int nt = 0; nt < 8; ++nt) {
      const bf16x8 b2 = *(const bf16x8*)(Ws + (nt * 16 + l16) * KPAD + kk * 32 + quad * 8);
      C[nt] = __builtin_amdgcn_mfma_f32_16x16x32_bf16(a, b2, C[nt], 0, 0, 0);
    }
  }

#pragma unroll
  for (int nt = 0; nt < 8; ++nt) {
    const int col = nt * 16 + l16;
    const float bias = k_b[col];
#pragma unroll
    for (int r2 = 0; r2 < 4; ++r2) {
      const size_t row = row0 + wv * 16 + quad * 4 + r2;
      kout[row * 128 + col] = f2bf16(C[nt][r2] + bias);
    }
  }
}

// ---------------------------------------------------------------------------
// MFMA GEMM: output projection, bf16x3 (fp32-accurate): o=hi+lo, w=hi+lo,
// C = oh*wh + oh*wl + ol*wh (lo*lo dropped, ~2^-18). fp32 out.
// ---------------------------------------------------------------------------
__global__ __launch_bounds__(256) void gemm_proj_mfma(
    const float* __restrict__ o, const ushort* __restrict__ wpT_hi,
    const ushort* __restrict__ wpT_lo, const float* __restrict__ proj_b,
    float* __restrict__ out) {
  __shared__ ushort Ah[64 * KPAD];
  __shared__ ushort Al[64 * KPAD];
  __shared__ ushort Wh[128 * KPAD];
  __shared__ ushort Wl[128 * KPAD];
  const int tid  = threadIdx.x;
  const int row0 = blockIdx.x * 64;
  {
    const int r = tid >> 2, cb = (tid & 3) * 32;
    const float4* xg = (const float4*)(o + (size_t)(row0 + r) * 128 + cb);
    uint4* dh = (uint4*)(Ah + r * KPAD + cb);
    uint4* dl = (uint4*)(Al + r * KPAD + cb);
#pragma unroll
    for (int i = 0; i < 4; ++i) {
      const float4 a = xg[2 * i], b2 = xg[2 * i + 1];
      const float vs[8] = {a.x, a.y, a.z, a.w, b2.x, b2.y, b2.z, b2.w};
      unsigned hw[4], lw[4];
#pragma unroll
      for (int e = 0; e < 4; ++e) {
        const unsigned short h0 = f2bf16(vs[2 * e]);
        const unsigned short h1 = f2bf16(vs[2 * e + 1]);
        hw[e] = (unsigned)h0 | ((unsigned)h1 << 16);
        lw[e] = (unsigned)f2bf16(vs[2 * e] - bf2f(h0)) |
                ((unsigned)f2bf16(vs[2 * e + 1] - bf2f(h1)) << 16);
      }
      dh[i] = make_uint4(hw[0], hw[1], hw[2], hw[3]);
      dl[i] = make_uint4(lw[0], lw[1], lw[2], lw[3]);
    }
  }
  {
    const uint4* wgh = (const uint4*)wpT_hi;
    const uint4* wgl = (const uint4*)wpT_lo;
    uint4* wh = (uint4*)Wh;
    uint4* wl = (uint4*)Wl;
    for (int i = tid; i < 2176; i += 256) { wh[i] = wgh[i]; wl[i] = wgl[i]; }
  }
  __syncthreads();

  const int wv = tid >> 6, lane = tid & 63, quad = lane >> 4, l16 = lane & 15;
  f32x4 C[8];
#pragma unroll
  for (int nt = 0; nt < 8; ++nt) C[nt] = (f32x4){0.f, 0.f, 0.f, 0.f};

#pragma unroll
  for (int kk = 0; kk < 4; ++kk) {
    const int aoff = (wv * 16 + l16) * KPAD + kk * 32 + quad * 8;
    const bf16x8 ah = *(const bf16x8*)(Ah + aoff);
    const bf16x8 al = *(const bf16x8*)(Al + aoff);
#pragma unroll
    for (int nt = 0; nt < 8; ++nt) {
      const int boff = (nt * 16 + l16) * KPAD + kk * 32 + quad * 8;
      const bf16x8 bh = *(const bf16x8*)(Wh + boff);
      const bf16x8 bl = *(const bf16x8*)(Wl + boff);
      C[nt] = __builtin_amdgcn_mfma_f32_16x16x32_bf16(ah, bh, C[nt], 0, 0, 0);
      C[nt] = __builtin_amdgcn_mfma_f32_16x16x32_bf16(ah, bl, C[nt], 0, 0, 0);
      C[nt] = __builtin_amdgcn_mfma_f32_16x16x32_bf16(al, bh, C[nt], 0, 0, 0);
    }
  }

#pragma unroll
  for (int nt = 0; nt < 8; ++nt) {
    const int col = nt * 16 + l16;
    const float bias = proj_b[col];
#pragma unroll
    for (int r2 = 0; r2 < 4; ++r2) {
      const size_t row = row0 + wv * 16 + quad * 4 + r2;
      out[row * 128 + col] = C[nt][r2] + bias;
    }
  }
}

// ---------------------------------------------------------------------------
// MFMA NA3D attention (union-GEMM). Block = 8x8 query tile (one b,t,head),
// 512 threads = 8 waves. Same structure as R6; q input is now bf16 with
// SCALE pre-folded -> A-frag is a single 16B load. Output to separate fp32 o.
// ---------------------------------------------------------------------------
__global__ __launch_bounds__(512, 1)
void na3d_tile(
    const ushort* __restrict__ qin,
    const ushort* __restrict__ kin,
    const ushort* __restrict__ vin,
    const float* __restrict__ rpb,
    float* __restrict__ oout) {
  __shared__ __align__(16) unsigned char smem[SMEM_BYTES];

  const int tid  = threadIdx.x;
  const int wv   = tid >> 6;
  const int lane = tid & 63;
  const int quad = lane >> 4;
  const int l16  = lane & 15;

  const int bx   = blockIdx.x;
  const int head = bx & 3;
  const int tile = bx >> 2;
  const int w0 = (tile & 7) << 3;
  const int h0 = ((tile >> 3) & 7) << 3;
  const int t  = (tile >> 6) & 7;
  const int b  = tile >> 9;

  const int st  = min(max(t - 1, 0), Tv - 3);
  const int u_h = min(max(h0 - 3, 0), Hv - U_H);
  const int u_w = min(max(w0 - 3, 0), Wv - U_W);
  const int rt_b = st - t + 2;   // 0..2

  // ---- Phase 1: stage K (swizzled), V (transposed), pads, LUT ----
  for (int i = tid; i < 2 * UPOS * 4; i += 512) {
    const bool isV = (i >= UPOS * 4);
    const int  j   = isV ? i - UPOS * 4 : i;
    const int  pos = j >> 2, c = j & 3;
    const int  ta  = pos / 196;
    const int  r   = pos - ta * 196;
    const int  rh  = r / 14;
    const int  ha  = u_h + rh;
    const int  wa  = u_w + (r - rh * 14);
    const size_t gpos = (((size_t)(b * Tv + st + ta) * Hv + ha) * Wv + wa);
    const uint4* src = (const uint4*)(isV ? (const void*)vin : (const void*)kin);
    const uint4 val = src[gpos * 16 + head * 4 + c];   // 16B = 8 bf16 = dims 8c..8c+7
    if (isV) {
      ushort* vt = (ushort*)(smem + VTOFF);
      unsigned vals[4] = {val.x, val.y, val.z, val.w};
#pragma unroll
      for (int m2 = 0; m2 < 4; ++m2) {
        const int d0 = 8 * c + 2 * m2;
        vt[(size_t)d0 * 616 + pos]       = (ushort)(vals[m2] & 0xffffu);
        vt[(size_t)(d0 + 1) * 616 + pos] = (ushort)(vals[m2] >> 16);
      }
    } else {
      const int slot = (c + (pos >> 2)) & 3;
      *(uint4*)(smem + KOFF + pos * 64 + slot * 16) = val;
    }
  }
  // Vt zero pad u in [588,616)
  if (tid < 448) {
    const int d = tid / 14, jj = tid - d * 14;
    *(unsigned*)(smem + VTOFF + d * 1232 + 1176 + jj * 4) = 0u;
  }
  // LUT[u]: f = ut*169+uh*13+uw, uh, uw packed
  for (int u = tid; u < 640; u += 512) {
    const int ut = (u >= 196) + (u >= 392) + (u >= 588);
    const int r2 = u - ut * 196;
    const int uh = r2 / 14;
    const int uw = r2 - uh * 14;
    const int f  = ut * 169 + uh * 13 + uw;
    ((unsigned*)(smem + LUTOFF))[u] =
        (unsigned)f | ((unsigned)uh << 16) | ((unsigned)uw << 24);
  }

  // A-frag: q bf16 pre-scaled -> single 16B load (overlaps staging)
  const int mtile = wv & 3;
  bf16x8 afrag;
  {
    const int q_a  = mtile * 16 + l16;
    const int qh_a = h0 + (q_a >> 3), qw_a = w0 + (q_a & 7);
    const size_t qpos_a = ((size_t)(b * Tv + t) * Hv + qh_a) * Wv + qw_a;
    afrag = *(const bf16x8*)(qin + qpos_a * 128 + head * 32 + quad * 8);
  }
  __syncthreads();

  // ---- Phase 2: QK MFMAs, raw f16 scores -> P ----
  {
    ushort* ph = (ushort*)(smem + POFF2);
    for (int nt = (wv >> 2); nt < 37; nt += 2) {
      const int u = nt * 16 + l16;
      const int slot = (quad + (u >> 2)) & 3;
      const bf16x8 bfrag = *(const bf16x8*)(smem + KOFF + u * 64 + slot * 16);
      f32x4 c = {0.f, 0.f, 0.f, 0.f};
      c = __builtin_amdgcn_mfma_f32_16x16x32_bf16(afrag, bfrag, c, 0, 0, 0);
#pragma unroll
      for (int r2 = 0; r2 < 4; ++r2) {
        const int qrow = mtile * 16 + quad * 4 + r2;
        ph[(size_t)qrow * 632 + u] = f2h(c[r2]);
      }
    }
  }
  __syncthreads();

  // ---- Phase 3: softmax (bias+mask+exp, no max-subtract) ----
  {
    const int qs  = tid >> 3, l8s = tid & 7;
    const int qh_s = h0 + (qs >> 3), qw_s = w0 + (qs & 7);
    const int sh_s = min(max(qh_s - 3, 0), Hv - 7);
    const int sw_s = min(max(qw_s - 3, 0), Wv - 7);
    const int dh_s = sh_s - u_h, dw_s = sw_s - u_w;
    const int Cq = rt_b * 169 + (u_h - qh_s + 6) * 13 + (u_w - qw_s + 6);
    const float* rpb_h = rpb + head * 845;
    unsigned char* Prow = smem + POFF2 + (size_t)qs * 1264;
    const unsigned* LUT = (const unsigned*)(smem + LUTOFF);

    float sum = 0.f;
#pragma unroll
    for (int jc = 0; jc < 10; ++jc) {
      const int cidx = l8s + 8 * jc;
      if (cidx < 79) {
        const int u0 = cidx * 8;
        uint4 pv = *(uint4*)(Prow + cidx * 16);
        const uint4 l0 = *(const uint4*)(LUT + u0);
        const uint4 l1 = *(const uint4*)(LUT + u0 + 4);
        unsigned pw[4] = {pv.x, pv.y, pv.z, pv.w};
        const unsigned lu[8] = {l0.x, l0.y, l0.z, l0.w, l1.x, l1.y, l1.z, l1.w};
#pragma unroll
        for (int e = 0; e < 8; ++e) {
          const unsigned lut = lu[e];
          const int uh = (lut >> 16) & 0xff;
          const int uw = lut >> 24;
          const bool valid = ((unsigned)(uh - dh_s) < 7u) &
                             ((unsigned)(uw - dw_s) < 7u) &
                             (u0 + e < UPOS);
          int idx = (int)(lut & 0xffffu) + Cq;
          idx = min(max(idx, 0), 844);
          const float bias = rpb_h[idx];
          const unsigned short hraw =
              (e & 1) ? (unsigned short)(pw[e >> 1] >> 16)
                      : (unsigned short)(pw[e >> 1] & 0xffffu);
          float s = h2f(hraw) + bias;
          s = valid ? s : -INFINITY;
          const float ex = __expf(s);
          sum += ex;
          const unsigned short ob = f2bf16(ex);
          if (e & 1) pw[e >> 1] = (pw[e >> 1] & 0x0000ffffu) | ((unsigned)ob << 16);
          else       pw[e >> 1] = (pw[e >> 1] & 0xffff0000u) | (unsigned)ob;
        }
        pv.x = pw[0]; pv.y = pw[1]; pv.z = pw[2]; pv.w = pw[3];
        *(uint4*)(Prow + cidx * 16) = pv;
      }
    }
    sum += __shfl_xor(sum, 1);
    sum += __shfl_xor(sum, 2);
    sum += __shfl_xor(sum, 4);
    if (l8s == 0) ((float*)(smem + KOFF))[qs] = 1.0f / sum;  // Ks region dead
  }
  __syncthreads();

  // ---- Phase 4: AV MFMAs + scaled store ----
  {
    const int mtA = wv >> 1, ntA = wv & 1;
    const int dcol = ntA * 16 + l16;
    const unsigned char* Abase = smem + POFF2 + (size_t)(mtA * 16 + l16) * 1264;
    const unsigned char* Bbase = smem + VTOFF + (size_t)dcol * 1232;
    f32x4 o = {0.f, 0.f, 0.f, 0.f};
#pragma unroll 4
    for (int kt = 0; kt < 19; ++kt) {
      const bf16x8 a  = *(const bf16x8*)(Abase + kt * 64 + quad * 16);
      const bf16x8 bb = *(const bf16x8*)(Bbase + kt * 64 + quad * 16);
      o = __builtin_amdgcn_mfma_f32_16x16x32_bf16(a, bb, o, 0, 0, 0);
    }
    const float* invArr = (const float*)(smem + KOFF);
#pragma unroll
    for (int r2 = 0; r2 < 4; ++r2) {
      const int qrow = mtA * 16 + quad * 4 + r2;
      const float val = o[r2] * invArr[qrow];
      const int qh2 = h0 + (qrow >> 3), qw2 = w0 + (qrow & 7);
      const size_t qp2 = ((size_t)(b * Tv + t) * Hv + qh2) * Wv + qw2;
      oout[qp2 * 128 + head * 32 + dcol] = val;
    }
  }
}

// ---------------------------------------------------------------------------
extern "C" void kernel_launch(void* const* d_in, const int* in_sizes, int n_in,
                              void* d_out, int out_size, void* d_ws, size_t ws_size,
                              hipStream_t stream) {
  const float* x      = (const float*)d_in[0];
  const float* y      = (const float*)d_in[1];
  const float* qv_w   = (const float*)d_in[2];
  const float* qv_b   = (const float*)d_in[3];
  const float* k_w    = (const float*)d_in[4];
  const float* k_b    = (const float*)d_in[5];
  const float* proj_w = (const float*)d_in[6];
  const float* proj_b = (const float*)d_in[7];
  const float* rpb    = (const float*)d_in[8];
  float* out = (float*)d_out;

  const size_t elems = (size_t)MPOS * 128;        // 8,388,608
  ushort* qbuf = (ushort*)d_ws;                   // 16.8 MB (bf16, SCALE folded)
  ushort* kbuf = qbuf + elems;                    // 16.8 MB
  ushort* vbuf = kbuf + elems;                    // 16.8 MB
  float*  obuf = (float*)(vbuf + elems);          // 33.5 MB (attn out fp32)
  ushort* wqvT   = (ushort*)(obuf + elems);       // 256*136*2 B
  ushort* wkT    = wqvT + 256 * KPAD;
  ushort* wpT_hi = wkT + 128 * KPAD;
  ushort* wpT_lo = wpT_hi + 128 * KPAD;           // total ~84 MB

  preconvert    <<<256,  256, 0, stream>>>(qv_w, k_w, proj_w, wqvT, wkT, wpT_hi, wpT_lo);
  gemm_qv_mfma  <<<1024, 256, 0, stream>>>(x, wqvT, qv_b, qbuf, vbuf);
  gemm_k_mfma   <<<1024, 256, 0, stream>>>(y, wkT, k_b, kbuf);
  na3d_tile     <<<4096, 512, 0, stream>>>(qbuf, kbuf, vbuf, rpb, obuf);
  gemm_proj_mfma<<<1024, 256, 0, stream>>>(obuf, wpT_hi, wpT_lo, proj_b, out);
}